// Round 1
// baseline (7660.052 us; speedup 1.0000x reference)
//
#include <hip/hip_runtime.h>
#include <math.h>

#define Hc 96
#define Wc 192
#define HWc (Hc * Wc)          // 18432
#define NOUT (19 * 384 * 768)  // 5603328

// ---------------------------------------------------------------------------
// Generic 3x3 conv, pad=1, N=1. Each block: 64 consecutive x for one (y, oc0..oc0+3).
// w indexed as w[oc * wstride + ci * 9 + k]  (wstride = Cin_total * 9; pass w
// pre-offset by ci0*9 for channel-sliced concat convs).
// Epilogue: accum ? (+= out) : (+= bias); then optional BN (gamma/beta).
// ---------------------------------------------------------------------------
__global__ __launch_bounds__(64) void conv3x3_k(
    const float* __restrict__ in, int Cin,
    const float* __restrict__ w, int wstride,
    const float* __restrict__ bias,
    const float* __restrict__ gamma, const float* __restrict__ beta,
    float* __restrict__ out, int accum)
{
    const int x = blockIdx.x * 64 + threadIdx.x;   // [0,192)
    const int y = blockIdx.y;                      // [0,96)
    const int oc0 = blockIdx.z * 4;
    const bool vy0 = (y > 0), vy2 = (y < Hc - 1);
    const bool vx0 = (x > 0), vx2 = (x < Wc - 1);
    const int p = y * Wc + x;

    float a0 = 0.f, a1 = 0.f, a2 = 0.f, a3 = 0.f;

    for (int ci = 0; ci < Cin; ++ci) {
        const float* ip = in + (size_t)ci * HWc + p;
        float v0 = (vy0 && vx0) ? ip[-Wc - 1] : 0.f;
        float v1 = vy0 ? ip[-Wc] : 0.f;
        float v2 = (vy0 && vx2) ? ip[-Wc + 1] : 0.f;
        float v3 = vx0 ? ip[-1] : 0.f;
        float v4 = ip[0];
        float v5 = vx2 ? ip[1] : 0.f;
        float v6 = (vy2 && vx0) ? ip[Wc - 1] : 0.f;
        float v7 = vy2 ? ip[Wc] : 0.f;
        float v8 = (vy2 && vx2) ? ip[Wc + 1] : 0.f;
        const float* wp = w + (size_t)ci * 9;
        {
            const float* wj = wp + (size_t)(oc0 + 0) * wstride;
            a0 += v0*wj[0] + v1*wj[1] + v2*wj[2] + v3*wj[3] + v4*wj[4]
                + v5*wj[5] + v6*wj[6] + v7*wj[7] + v8*wj[8];
        }
        {
            const float* wj = wp + (size_t)(oc0 + 1) * wstride;
            a1 += v0*wj[0] + v1*wj[1] + v2*wj[2] + v3*wj[3] + v4*wj[4]
                + v5*wj[5] + v6*wj[6] + v7*wj[7] + v8*wj[8];
        }
        {
            const float* wj = wp + (size_t)(oc0 + 2) * wstride;
            a2 += v0*wj[0] + v1*wj[1] + v2*wj[2] + v3*wj[3] + v4*wj[4]
                + v5*wj[5] + v6*wj[6] + v7*wj[7] + v8*wj[8];
        }
        {
            const float* wj = wp + (size_t)(oc0 + 3) * wstride;
            a3 += v0*wj[0] + v1*wj[1] + v2*wj[2] + v3*wj[3] + v4*wj[4]
                + v5*wj[5] + v6*wj[6] + v7*wj[7] + v8*wj[8];
        }
    }

    float acc[4];
    acc[0] = a0; acc[1] = a1; acc[2] = a2; acc[3] = a3;
#pragma unroll
    for (int j = 0; j < 4; ++j) {
        const int oc = oc0 + j;
        float r = acc[j];
        if (accum) r += out[(size_t)oc * HWc + p];
        else if (bias) r += bias[oc];
        if (gamma) r = r * gamma[oc] + beta[oc];
        out[(size_t)oc * HWc + p] = r;
    }
}

// ---------------------------------------------------------------------------
// 1x1 conv: one oc per block-z. w[oc*Cin + ci].
// ---------------------------------------------------------------------------
__global__ __launch_bounds__(64) void conv1x1_k(
    const float* __restrict__ in, int Cin,
    const float* __restrict__ w,
    const float* __restrict__ bias,
    const float* __restrict__ gamma, const float* __restrict__ beta,
    float* __restrict__ out)
{
    const int x = blockIdx.x * 64 + threadIdx.x;
    const int y = blockIdx.y;
    const int oc = blockIdx.z;
    const int p = y * Wc + x;
    const float* wp = w + (size_t)oc * Cin;
    float acc = 0.f;
    for (int ci = 0; ci < Cin; ++ci)
        acc += in[(size_t)ci * HWc + p] * wp[ci];
    if (bias) acc += bias[oc];
    if (gamma) acc = acc * gamma[oc] + beta[oc];
    out[(size_t)oc * HWc + p] = acc;
}

// ---------------------------------------------------------------------------
// softmax over 81 channels, in place. One thread per pixel.
// ---------------------------------------------------------------------------
__global__ __launch_bounds__(256) void softmax81_k(float* __restrict__ t)
{
    const int p = blockIdx.x * 256 + threadIdx.x;
    if (p >= HWc) return;
    float m = -1e30f;
    for (int k = 0; k < 81; ++k) m = fmaxf(m, t[(size_t)k * HWc + p]);
    float s = 0.f;
    for (int k = 0; k < 81; ++k) s += __expf(t[(size_t)k * HWc + p] - m);
    const float inv = 1.f / s;
    for (int k = 0; k < 81; ++k)
        t[(size_t)k * HWc + p] = __expf(t[(size_t)k * HWc + p] - m) * inv;
}

// ---------------------------------------------------------------------------
// elementwise a = x - y
// ---------------------------------------------------------------------------
__global__ __launch_bounds__(256) void diff_k(const float* __restrict__ x,
                                              const float* __restrict__ y,
                                              float* __restrict__ o, int n)
{
    int i = blockIdx.x * 256 + threadIdx.x;
    if (i < n) o[i] = x[i] - y[i];
}

// ---------------------------------------------------------------------------
// dynamic 9x9 local filtering: out[c,y,x] = sum_k deep[c, y+k/9-4, x+k%9-4] * ker[k,y,x]
// Block: 64 threads along x, one y. Kernel taps held in registers (unrolled).
// ---------------------------------------------------------------------------
__global__ __launch_bounds__(64) void propagate_k(
    const float* __restrict__ deep, const float* __restrict__ ker,
    float* __restrict__ out)
{
    const int x = blockIdx.x * 64 + threadIdx.x;
    const int y = blockIdx.y;
    const int p = y * Wc + x;

    float kr[81];
#pragma unroll
    for (int k = 0; k < 81; ++k) kr[k] = ker[(size_t)k * HWc + p];

    for (int c = 0; c < 256; ++c) {
        const float* bp = deep + (size_t)c * HWc + p;
        float acc = 0.f;
#pragma unroll
        for (int k = 0; k < 81; ++k) {
            const int dy = k / 9 - 4, dx = k % 9 - 4;
            const bool ok = (y + dy >= 0) && (y + dy < Hc) && (x + dx >= 0) && (x + dx < Wc);
            float v = ok ? bp[dy * Wc + dx] : 0.f;
            acc += v * kr[k];
        }
        out[(size_t)c * HWc + p] = acc;
    }
}

// ---------------------------------------------------------------------------
// per-channel spatial sum: r[c] = sum_p t[c,p]
// ---------------------------------------------------------------------------
__global__ __launch_bounds__(256) void chanreduce_k(const float* __restrict__ t,
                                                    float* __restrict__ r)
{
    __shared__ float buf[256];
    const int c = blockIdx.x;
    float s = 0.f;
    for (int i = threadIdx.x; i < HWc; i += 256) s += t[(size_t)c * HWc + i];
    buf[threadIdx.x] = s;
    __syncthreads();
    for (int st = 128; st > 0; st >>= 1) {
        if (threadIdx.x < st) buf[threadIdx.x] += buf[threadIdx.x + st];
        __syncthreads();
    }
    if (threadIdx.x == 0) r[c] = buf[0];
}

// deviation = dot(mean_c, fc_w) + fc_b  (single block of 256)
__global__ __launch_bounds__(256) void deviation_k(const float* __restrict__ r,
                                                   const float* __restrict__ fcw,
                                                   const float* __restrict__ fcb,
                                                   float* __restrict__ o)
{
    __shared__ float buf[256];
    buf[threadIdx.x] = r[threadIdx.x] * fcw[threadIdx.x];
    __syncthreads();
    for (int st = 128; st > 0; st >>= 1) {
        if (threadIdx.x < st) buf[threadIdx.x] += buf[threadIdx.x + st];
        __syncthreads();
    }
    if (threadIdx.x == 0) o[0] = buf[0] * (1.f / (float)HWc) + fcb[0];
}

// ---------------------------------------------------------------------------
// bilinear 4x upsample, half-pixel centers, edge clamp (== jax renormalized)
// in: (19,96,192) -> out: (19,384,768)
// ---------------------------------------------------------------------------
__global__ __launch_bounds__(256) void upsample_k(const float* __restrict__ in,
                                                  float* __restrict__ outp)
{
    const int idx = blockIdx.x * 256 + threadIdx.x;
    if (idx >= NOUT) return;
    const int ox = idx % 768;
    const int t = idx / 768;
    const int oy = t % 384;
    const int c = t / 384;

    const float fx = (ox + 0.5f) * 0.25f - 0.5f;
    const float fy = (oy + 0.5f) * 0.25f - 0.5f;
    const int x0 = (int)floorf(fx);
    const int y0 = (int)floorf(fy);
    const float wx = fx - (float)x0;
    const float wy = fy - (float)y0;
    const int x0c = min(max(x0, 0), Wc - 1), x1c = min(max(x0 + 1, 0), Wc - 1);
    const int y0c = min(max(y0, 0), Hc - 1), y1c = min(max(y0 + 1, 0), Hc - 1);

    const float* ip = in + (size_t)c * HWc;
    const float v00 = ip[y0c * Wc + x0c], v01 = ip[y0c * Wc + x1c];
    const float v10 = ip[y1c * Wc + x0c], v11 = ip[y1c * Wc + x1c];
    outp[idx] = (1.f - wy) * ((1.f - wx) * v00 + wx * v01)
              + wy * ((1.f - wx) * v10 + wx * v11);
}

// ---------------------------------------------------------------------------
extern "C" void kernel_launch(void* const* d_in, const int* in_sizes, int n_in,
                              void* d_out, int out_size, void* d_ws, size_t ws_size,
                              hipStream_t stream)
{
    const float* f1_deep = (const float*)d_in[0];
    const float* f1_low  = (const float*)d_in[1];
    const float* f2_low  = (const float*)d_in[2];
    const float* wp_c1_w = (const float*)d_in[3];
    const float* wp_c1_b = (const float*)d_in[4];
    const float* wp_c2_w = (const float*)d_in[5];
    const float* wp_c2_b = (const float*)d_in[6];
    const float* wp_fc_w = (const float*)d_in[7];
    const float* wp_fc_b = (const float*)d_in[8];
    const float* sch_c1_w = (const float*)d_in[9];
    // d_in[10] sch_c1_b cancels in the difference
    const float* sch_c2_w = (const float*)d_in[11];
    const float* sch_c2_b = (const float*)d_in[12];
    const float* sch_fc_w = (const float*)d_in[13];
    const float* sch_fc_b = (const float*)d_in[14];
    const float* ad_c1_w = (const float*)d_in[15];
    const float* ad_c1_b = (const float*)d_in[16];
    const float* ad_c2_w = (const float*)d_in[17];
    const float* ad_c2_b = (const float*)d_in[18];
    const float* ad_c3_w = (const float*)d_in[19];
    const float* ad_c3_b = (const float*)d_in[20];
    const float* rc_w    = (const float*)d_in[21];
    const float* rc_b    = (const float*)d_in[22];
    const float* rc_g    = (const float*)d_in[23];
    const float* rc_beta = (const float*)d_in[24];
    const float* lc1_w   = (const float*)d_in[25];
    const float* lc1_b   = (const float*)d_in[26];
    const float* lc1_g   = (const float*)d_in[27];
    const float* lc1_beta= (const float*)d_in[28];
    const float* lc2_w   = (const float*)d_in[29];
    const float* lc2_b   = (const float*)d_in[30];
    const float* lc2_g   = (const float*)d_in[31];
    const float* lc2_beta= (const float*)d_in[32];
    const float* lc3_w   = (const float*)d_in[33];
    const float* lc3_b   = (const float*)d_in[34];

    float* out = (float*)d_out;
    float* ws = (float*)d_ws;
    float* A = ws;                          // 256*HW
    float* B = A + (size_t)256 * HWc;       // 256*HW
    float* C = B + (size_t)256 * HWc;       // 256*HW
    float* D = C + (size_t)256 * HWc;       // 81*HW (kernel81, later low48)
    float* E = D + (size_t)81 * HWc;        // 19*HW logits
    float* R = E + (size_t)19 * HWc;        // 256 reduce scratch

    const dim3 g3(3, 96, 64);   // conv3x3: Cout=256 -> 64 z-blocks of 4 oc
    const dim3 b64(64);
    const dim3 b256(256);

    // --- WeightPredictor ---
    conv3x3_k<<<g3, b64, 0, stream>>>(f1_low, 256, wp_c1_w, 2304, wp_c1_b, nullptr, nullptr, A, 0);
    conv3x3_k<<<g3, b64, 0, stream>>>(f2_low, 256, wp_c1_w, 2304, wp_c1_b, nullptr, nullptr, B, 0);
    conv3x3_k<<<g3, b64, 0, stream>>>(A, 256, wp_c2_w,            4608, wp_c2_b, nullptr, nullptr, C, 0);
    conv3x3_k<<<g3, b64, 0, stream>>>(B, 256, wp_c2_w + 256 * 9,  4608, nullptr, nullptr, nullptr, C, 1);
    conv1x1_k<<<dim3(3, 96, 81), b64, 0, stream>>>(C, 256, wp_fc_w, wp_fc_b, nullptr, nullptr, D);
    softmax81_k<<<dim3(HWc / 256), b256, 0, stream>>>(D);

    // --- AdaptiveScheduler (conv bias cancels in the difference) ---
    diff_k<<<dim3((256 * HWc) / 256), b256, 0, stream>>>(f1_low, f2_low, A, 256 * HWc);
    conv3x3_k<<<g3, b64, 0, stream>>>(A, 256, sch_c1_w, 2304, nullptr, nullptr, nullptr, B, 0);
    conv3x3_k<<<g3, b64, 0, stream>>>(B, 256, sch_c2_w, 2304, sch_c2_b, nullptr, nullptr, C, 0);
    chanreduce_k<<<dim3(256), b256, 0, stream>>>(C, R);
    deviation_k<<<dim3(1), b256, 0, stream>>>(R, sch_fc_w, sch_fc_b, out + NOUT);

    // --- Propagation ---
    propagate_k<<<dim3(3, 96), b64, 0, stream>>>(f1_deep, D, A);

    // --- AdaptNet: conv(cat[f2_low, prop]) as two sliced passes ---
    conv3x3_k<<<g3, b64, 0, stream>>>(f2_low, 256, ad_c1_w,           4608, ad_c1_b, nullptr, nullptr, B, 0);
    conv3x3_k<<<g3, b64, 0, stream>>>(A,      256, ad_c1_w + 256 * 9, 4608, nullptr, nullptr, nullptr, B, 1);
    conv3x3_k<<<g3, b64, 0, stream>>>(B, 256, ad_c2_w, 2304, ad_c2_b, nullptr, nullptr, C, 0);
    conv3x3_k<<<g3, b64, 0, stream>>>(C, 256, ad_c3_w, 2304, ad_c3_b, nullptr, nullptr, A, 0);

    // --- reduce_conv2 (1x1 + BN) ---
    conv1x1_k<<<dim3(3, 96, 48), b64, 0, stream>>>(f2_low, 256, rc_w, rc_b, rc_g, rc_beta, D);

    // --- last_conv ---
    conv3x3_k<<<g3, b64, 0, stream>>>(A, 256, lc1_w,           2736, lc1_b, nullptr, nullptr, B, 0);
    conv3x3_k<<<g3, b64, 0, stream>>>(D, 48,  lc1_w + 256 * 9, 2736, nullptr, lc1_g, lc1_beta, B, 1);
    conv3x3_k<<<g3, b64, 0, stream>>>(B, 256, lc2_w, 2304, lc2_b, lc2_g, lc2_beta, C, 0);
    conv1x1_k<<<dim3(3, 96, 19), b64, 0, stream>>>(C, 256, lc3_w, lc3_b, nullptr, nullptr, E);

    // --- 4x bilinear upsample ---
    upsample_k<<<dim3(NOUT / 256), b256, 0, stream>>>(E, out);
}

// Round 2
// 2018.562 us; speedup vs baseline: 3.7948x; 3.7948x over previous
//
#include <hip/hip_runtime.h>
#include <math.h>

#define HWIMG 18432          // 96*192
#define W2 194               // padded width, pad=1
#define H2 98
#define NPX1 (H2 * W2)       // 19012 padded pixels, pad=1
#define W4 200               // padded width, pad=4
#define H4 104
#define NPX4 (H4 * W4)       // 20800 padded pixels, pad=4
#define NOUT (19 * 384 * 768)

typedef short bf16x8 __attribute__((ext_vector_type(8)));
typedef float f32x16 __attribute__((ext_vector_type(16)));

__device__ __forceinline__ ushort bf16r(float f) {
    union { float f; unsigned u; } a; a.f = f;
    unsigned u = a.u;
    return (ushort)((u + 0x7fffu + ((u >> 16) & 1u)) >> 16);
}
__device__ __forceinline__ float b2f(ushort u) {
    union { unsigned i; float f; } a; a.i = ((unsigned)u) << 16;
    return a.f;
}
__device__ __forceinline__ bf16x8 ld8(const ushort* p) {
    return *reinterpret_cast<const bf16x8*>(p);
}

// ---------------------------------------------------------------------------
// NCHW f32 (C=256) -> padded NHWC bf16, full-buffer write (borders zeroed).
// P = halo. Optional src2: value = src - src2.
// ---------------------------------------------------------------------------
__global__ __launch_bounds__(256) void xform_k(const float* __restrict__ src,
                                               const float* __restrict__ src2,
                                               ushort* __restrict__ dst, int P)
{
    const int Wp = 192 + 2 * P;
    const int total = (96 + 2 * P) * Wp;
    const int px = blockIdx.x * 8 + (threadIdx.x >> 5);
    const int c8 = (threadIdx.x & 31) * 8;
    if (px >= total) return;
    const int yP = px / Wp, xP = px % Wp;
    const int y = yP - P, x = xP - P;
    ushort v[8];
    if (y >= 0 && y < 96 && x >= 0 && x < 192) {
        const int p = y * 192 + x;
#pragma unroll
        for (int j = 0; j < 8; ++j) {
            float f = src[(size_t)(c8 + j) * HWIMG + p];
            if (src2) f -= src2[(size_t)(c8 + j) * HWIMG + p];
            v[j] = bf16r(f);
        }
    } else {
#pragma unroll
        for (int j = 0; j < 8; ++j) v[j] = 0;
    }
    *reinterpret_cast<uint4*>(dst + (size_t)px * 256 + c8) = *reinterpret_cast<uint4*>(v);
}

// ---------------------------------------------------------------------------
// Zero the pad=1 border of a padded-NHWC buffer with channel stride Cst.
// 580 border pixels.
// ---------------------------------------------------------------------------
__global__ __launch_bounds__(256) void borderzero_k(ushort* __restrict__ buf, int Cst)
{
    const int cg = Cst / 8;
    const int idx = blockIdx.x * 256 + threadIdx.x;
    if (idx >= 580 * cg) return;
    const int pi = idx / cg;
    const int c8 = (idx % cg) * 8;
    int pp;
    if (pi < 194) pp = pi;
    else if (pi < 388) pp = 97 * 194 + (pi - 194);
    else if (pi < 484) pp = (pi - 388 + 1) * 194;
    else pp = (pi - 484 + 1) * 194 + 193;
    uint4 z = {0, 0, 0, 0};
    *reinterpret_cast<uint4*>(buf + (size_t)pp * Cst + c8) = z;
}

// ---------------------------------------------------------------------------
// Weight transform: OIHW f32 -> wt[tap][ocp][Kp] bf16 (+ folded bias f32).
// k < ncb0*32 maps to input0 channel k (valid if < CinR0);
// k >= ncb0*32 maps to input1 channel k-ncb0*32 (valid if < CinR1).
// gamma folds BN scale into weights; bias = gamma*b+beta.
// ---------------------------------------------------------------------------
__global__ __launch_bounds__(256) void wtx_k(const float* __restrict__ w,
                                             const float* __restrict__ b,
                                             const float* __restrict__ g,
                                             const float* __restrict__ beta,
                                             ushort* __restrict__ wt,
                                             float* __restrict__ biasout,
                                             int CoutR, int Coutp, int CinR0, int ncb0,
                                             int CinR1, int Kp, int ntaps)
{
    const int idx = blockIdx.x * 256 + threadIdx.x;
    const int total = ntaps * Coutp * Kp;
    const int CinT = CinR0 + CinR1;
    if (idx < total) {
        const int k = idx % Kp;
        const int oc = (idx / Kp) % Coutp;
        const int tap = idx / (Kp * Coutp);
        float val = 0.f;
        if (oc < CoutR) {
            int cit = -1;
            const int kb = ncb0 * 32;
            if (k < kb) { if (k < CinR0) cit = k; }
            else { const int k1 = k - kb; if (k1 < CinR1) cit = CinR0 + k1; }
            if (cit >= 0) {
                val = w[((size_t)oc * CinT + cit) * ntaps + tap];
                if (g) val *= g[oc];
            }
        }
        wt[idx] = bf16r(val);
    } else if (idx < total + Coutp) {
        const int oc = idx - total;
        float v = 0.f;
        if (oc < CoutR) {
            v = b ? b[oc] : 0.f;
            if (g) v = v * g[oc] + beta[oc];
        }
        biasout[oc] = v;
    }
}

// ---------------------------------------------------------------------------
// Implicit-GEMM conv via MFMA 32x32x16 bf16.
// M = pixels, N = out channels, K = Cin*ntaps.
// Inputs are padded NHWC bf16 (pad=1). Output: padded NHWC bf16, interior only.
// Block: 256 thr = 4 waves; tile 128 px (2 rows x 64) x 64 oc; wave 64px x 32oc.
// grid = (3, 48, Coutp/64).
// ---------------------------------------------------------------------------
template<int NTAPS>
__device__ __forceinline__ void conv_part(
    f32x16& acc0, f32x16& acc1,
    const ushort* __restrict__ in, int Cst, int ncb,
    const ushort* __restrict__ wB, int KOff, int Kp, int Coutp,
    int rowbase, int xlane, int lhi8)
{
    const ushort* aB = in + ((size_t)rowbase + xlane) * Cst + lhi8;
    for (int cb = 0; cb < ncb; ++cb) {
        const int cio = cb * 32;
#pragma unroll
        for (int t = 0; t < NTAPS; ++t) {
            const int dy = (NTAPS == 9) ? (t / 3 - 1) : 0;
            const int dx = (NTAPS == 9) ? (t % 3 - 1) : 0;
            const ushort* ap = aB + (ptrdiff_t)(dy * 194 + dx) * Cst + cio;
            bf16x8 a00 = ld8(ap);
            bf16x8 a01 = ld8(ap + 16);
            bf16x8 a10 = ld8(ap + 32 * Cst);
            bf16x8 a11 = ld8(ap + 32 * Cst + 16);
            const ushort* bp = wB + (size_t)t * Coutp * Kp + KOff + cio;
            bf16x8 b0 = ld8(bp);
            bf16x8 b1 = ld8(bp + 16);
            acc0 = __builtin_amdgcn_mfma_f32_32x32x16_bf16(a00, b0, acc0, 0, 0, 0);
            acc0 = __builtin_amdgcn_mfma_f32_32x32x16_bf16(a01, b1, acc0, 0, 0, 0);
            acc1 = __builtin_amdgcn_mfma_f32_32x32x16_bf16(a10, b0, acc1, 0, 0, 0);
            acc1 = __builtin_amdgcn_mfma_f32_32x32x16_bf16(a11, b1, acc1, 0, 0, 0);
        }
    }
}

template<int NTAPS>
__global__ __launch_bounds__(256) void conv_mfma_k(
    const ushort* __restrict__ in0, int Cst0, int ncb0,
    const ushort* __restrict__ in1, int Cst1, int ncb1,
    const ushort* __restrict__ wt, int Kp,
    const float* __restrict__ bias,
    ushort* __restrict__ out, int CoutSt)
{
    const int x0 = blockIdx.x * 64 + 1;       // padded x base
    const int y0 = blockIdx.y * 2 + 1;        // padded y base
    const int Coutp = gridDim.z * 64;
    const int oc0 = blockIdx.z * 64;
    const int lane = threadIdx.x & 63;
    const int wave = threadIdx.x >> 6;
    const int wr = wave >> 1;                 // row within tile
    const int wn = wave & 1;                  // oc half
    const int l31 = lane & 31, lhi = lane >> 5;

    f32x16 acc0 = 0.f, acc1 = 0.f;

    const int ocw = oc0 + wn * 32 + l31;
    const ushort* wB = wt + (size_t)ocw * Kp + lhi * 8;
    const int rowbase = (y0 + wr) * W2;
    const int xlane = x0 + l31;

    conv_part<NTAPS>(acc0, acc1, in0, Cst0, ncb0, wB, 0, Kp, Coutp, rowbase, xlane, lhi * 8);
    if (in1)
        conv_part<NTAPS>(acc0, acc1, in1, Cst1, ncb1, wB, ncb0 * 32, Kp, Coutp, rowbase, xlane, lhi * 8);

    const float bs = bias[ocw];
    const size_t rb = (size_t)(y0 + wr) * W2;
#pragma unroll
    for (int r = 0; r < 16; ++r) {
        const int r32 = (r & 3) + 8 * (r >> 2) + 4 * lhi;
        out[(rb + x0 + r32) * CoutSt + ocw] = bf16r(acc0[r] + bs);
        out[(rb + x0 + 32 + r32) * CoutSt + ocw] = bf16r(acc1[r] + bs);
    }
}

// ---------------------------------------------------------------------------
// Softmax over 81 channels (padded NHWC, Cst=128), in place, interior pixels.
// ---------------------------------------------------------------------------
__global__ __launch_bounds__(256) void softmax81_k(ushort* __restrict__ t)
{
    const int p = blockIdx.x * 256 + threadIdx.x;
    if (p >= HWIMG) return;
    const int y = p / 192, x = p % 192;
    ushort* row = t + ((size_t)(y + 1) * W2 + (x + 1)) * 128;
    float v[81];
    float m = -1e30f;
#pragma unroll
    for (int k = 0; k < 81; ++k) { v[k] = b2f(row[k]); m = fmaxf(m, v[k]); }
    float s = 0.f;
#pragma unroll
    for (int k = 0; k < 81; ++k) { v[k] = __expf(v[k] - m); s += v[k]; }
    const float inv = 1.f / s;
#pragma unroll
    for (int k = 0; k < 81; ++k) row[k] = bf16r(v[k] * inv);
}

// ---------------------------------------------------------------------------
// Propagation: out[p][c] = sum_k deep[y+dy][x+dx][c] * ker[p][k]
// deep: pad4 NHWC bf16 [104][200][256]; ker: pad1 NHWC bf16 Cst=128 (81 used)
// out: pad1 NHWC bf16 Cst=256, FULL write (borders zeroed).
// ---------------------------------------------------------------------------
__global__ __launch_bounds__(256) void prop_k(const ushort* __restrict__ deep,
                                              const ushort* __restrict__ ker,
                                              ushort* __restrict__ out)
{
    __shared__ float kl[8][81];
    const int pxb = blockIdx.x * 8;
    const int t = threadIdx.x;
    for (int i = t; i < 8 * 81; i += 256) {
        const int pp = pxb + i / 81, k = i % 81;
        float kv = 0.f;
        if (pp < NPX1) {
            const int yP = pp / W2, xP = pp % W2;
            if (yP >= 1 && yP <= 96 && xP >= 1 && xP <= 192)
                kv = b2f(ker[((size_t)yP * W2 + xP) * 128 + k]);
        }
        kl[i / 81][k] = kv;
    }
    __syncthreads();
    const int pi = t >> 5;
    const int c8 = (t & 31) * 8;
    const int pp = pxb + pi;
    if (pp >= NPX1) return;
    const int yP = pp / W2, xP = pp % W2;
    ushort* op = out + (size_t)pp * 256 + c8;
    if (yP < 1 || yP > 96 || xP < 1 || xP > 192) {
        uint4 z = {0, 0, 0, 0};
        *reinterpret_cast<uint4*>(op) = z;
        return;
    }
    const int y = yP - 1, x = xP - 1;
    float acc[8];
#pragma unroll
    for (int j = 0; j < 8; ++j) acc[j] = 0.f;
    const ushort* dbase = deep + ((size_t)(y + 4) * W4 + (x + 4)) * 256 + c8;
#pragma unroll
    for (int k = 0; k < 81; ++k) {
        const int dy = k / 9 - 4, dx = k % 9 - 4;
        const float kv = kl[pi][k];
        bf16x8 d = ld8(dbase + (ptrdiff_t)(dy * W4 + dx) * 256);
#pragma unroll
        for (int j = 0; j < 8; ++j) acc[j] += b2f((ushort)d[j]) * kv;
    }
    ushort v[8];
#pragma unroll
    for (int j = 0; j < 8; ++j) v[j] = bf16r(acc[j]);
    *reinterpret_cast<uint4*>(op) = *reinterpret_cast<uint4*>(v);
}

// ---------------------------------------------------------------------------
// Per-row channel sums of padded NHWC bf16 (Cst=256): partial[y][c]
// ---------------------------------------------------------------------------
__global__ __launch_bounds__(256) void rowsum_k(const ushort* __restrict__ t,
                                                float* __restrict__ partial)
{
    const int y = blockIdx.x, c = threadIdx.x;
    const ushort* row = t + ((size_t)(y + 1) * W2 + 1) * 256 + c;
    float s = 0.f;
    for (int x = 0; x < 192; ++x) s += b2f(row[(size_t)x * 256]);
    partial[y * 256 + c] = s;
}

__global__ __launch_bounds__(256) void dev_k(const float* __restrict__ partial,
                                             const float* __restrict__ fcw,
                                             const float* __restrict__ fcb,
                                             float* __restrict__ o)
{
    __shared__ float buf[256];
    const int c = threadIdx.x;
    float s = 0.f;
    for (int y = 0; y < 96; ++y) s += partial[y * 256 + c];
    buf[c] = s * fcw[c];
    __syncthreads();
    for (int st = 128; st > 0; st >>= 1) {
        if (c < st) buf[c] += buf[c + st];
        __syncthreads();
    }
    if (c == 0) o[0] = buf[0] * (1.f / (float)HWIMG) + fcb[0];
}

// ---------------------------------------------------------------------------
// 4x bilinear upsample from padded NHWC bf16 (Cst=64, 19 channels) -> f32 NCHW
// ---------------------------------------------------------------------------
__global__ __launch_bounds__(256) void upsample_k(const ushort* __restrict__ in,
                                                  float* __restrict__ outp)
{
    const int idx = blockIdx.x * 256 + threadIdx.x;
    if (idx >= NOUT) return;
    const int ox = idx % 768;
    const int t = idx / 768;
    const int oy = t % 384;
    const int c = t / 384;

    const float fx = (ox + 0.5f) * 0.25f - 0.5f;
    const float fy = (oy + 0.5f) * 0.25f - 0.5f;
    const int x0 = (int)floorf(fx);
    const int y0 = (int)floorf(fy);
    const float wx = fx - (float)x0;
    const float wy = fy - (float)y0;
    const int x0c = min(max(x0, 0), 191), x1c = min(max(x0 + 1, 0), 191);
    const int y0c = min(max(y0, 0), 95), y1c = min(max(y0 + 1, 0), 95);

    const float v00 = b2f(in[((size_t)(y0c + 1) * W2 + (x0c + 1)) * 64 + c]);
    const float v01 = b2f(in[((size_t)(y0c + 1) * W2 + (x1c + 1)) * 64 + c]);
    const float v10 = b2f(in[((size_t)(y1c + 1) * W2 + (x0c + 1)) * 64 + c]);
    const float v11 = b2f(in[((size_t)(y1c + 1) * W2 + (x1c + 1)) * 64 + c]);
    outp[idx] = (1.f - wy) * ((1.f - wx) * v00 + wx * v01)
              + wy * ((1.f - wx) * v10 + wx * v11);
}

// ---------------------------------------------------------------------------
extern "C" void kernel_launch(void* const* d_in, const int* in_sizes, int n_in,
                              void* d_out, int out_size, void* d_ws, size_t ws_size,
                              hipStream_t stream)
{
    const float* f1_deep = (const float*)d_in[0];
    const float* f1_low  = (const float*)d_in[1];
    const float* f2_low  = (const float*)d_in[2];
    const float* wp_c1_w = (const float*)d_in[3];
    const float* wp_c1_b = (const float*)d_in[4];
    const float* wp_c2_w = (const float*)d_in[5];
    const float* wp_c2_b = (const float*)d_in[6];
    const float* wp_fc_w = (const float*)d_in[7];
    const float* wp_fc_b = (const float*)d_in[8];
    const float* sch_c1_w = (const float*)d_in[9];
    const float* sch_c2_w = (const float*)d_in[11];
    const float* sch_c2_b = (const float*)d_in[12];
    const float* sch_fc_w = (const float*)d_in[13];
    const float* sch_fc_b = (const float*)d_in[14];
    const float* ad_c1_w = (const float*)d_in[15];
    const float* ad_c1_b = (const float*)d_in[16];
    const float* ad_c2_w = (const float*)d_in[17];
    const float* ad_c2_b = (const float*)d_in[18];
    const float* ad_c3_w = (const float*)d_in[19];
    const float* ad_c3_b = (const float*)d_in[20];
    const float* rc_w    = (const float*)d_in[21];
    const float* rc_b    = (const float*)d_in[22];
    const float* rc_g    = (const float*)d_in[23];
    const float* rc_beta = (const float*)d_in[24];
    const float* lc1_w   = (const float*)d_in[25];
    const float* lc1_b   = (const float*)d_in[26];
    const float* lc1_g   = (const float*)d_in[27];
    const float* lc1_beta= (const float*)d_in[28];
    const float* lc2_w   = (const float*)d_in[29];
    const float* lc2_b   = (const float*)d_in[30];
    const float* lc2_g   = (const float*)d_in[31];
    const float* lc2_beta= (const float*)d_in[32];
    const float* lc3_w   = (const float*)d_in[33];
    const float* lc3_b   = (const float*)d_in[34];

    float* out = (float*)d_out;
    char* ws = (char*)d_ws;

    const size_t BIGB = (size_t)NPX4 * 256 * 2;           // 10,649,600 B
    ushort* F1  = (ushort*)(ws);
    ushort* F2  = (ushort*)(ws + BIGB);
    ushort* U   = (ushort*)(ws + 2 * BIGB);
    ushort* V   = (ushort*)(ws + 3 * BIGB);
    ushort* W   = (ushort*)(ws + 4 * BIGB);
    ushort* K81 = (ushort*)(ws + 5 * BIGB);               // NPX1*128*2 = 4,866,560
    ushort* L48 = (ushort*)(ws + 5 * BIGB + (size_t)NPX1 * 128 * 2);   // NPX1*64*2
    ushort* WT  = (ushort*)(ws + 5 * BIGB + (size_t)NPX1 * 192 * 2);   // 2,359,296 B max
    float* BIAS = (float*)((char*)WT + 9 * 256 * 512 * 2);
    float* PART = BIAS + 256;

    const dim3 b256(256);
    const dim3 gX1(2377), gX4(2600);
    const dim3 gC4(3, 48, 4), gC2(3, 48, 2), gC1(3, 48, 1);

    // transforms of inputs
    xform_k<<<gX1, b256, 0, stream>>>(f1_low, nullptr, F1, 1);
    xform_k<<<gX1, b256, 0, stream>>>(f2_low, nullptr, F2, 1);
    borderzero_k<<<73, b256, 0, stream>>>(U, 256);
    borderzero_k<<<73, b256, 0, stream>>>(V, 256);
    borderzero_k<<<73, b256, 0, stream>>>(W, 256);
    borderzero_k<<<19, b256, 0, stream>>>(L48, 64);

    // --- WeightPredictor ---
    wtx_k<<<dim3((9*256*256 + 256 + 255)/256), b256, 0, stream>>>(
        wp_c1_w, wp_c1_b, nullptr, nullptr, WT, BIAS, 256, 256, 256, 8, 0, 256, 9);
    conv_mfma_k<9><<<gC4, b256, 0, stream>>>(F1, 256, 8, nullptr, 0, 0, WT, 256, BIAS, U, 256);
    conv_mfma_k<9><<<gC4, b256, 0, stream>>>(F2, 256, 8, nullptr, 0, 0, WT, 256, BIAS, V, 256);
    wtx_k<<<dim3((9*256*512 + 256 + 255)/256), b256, 0, stream>>>(
        wp_c2_w, wp_c2_b, nullptr, nullptr, WT, BIAS, 256, 256, 256, 8, 256, 512, 9);
    conv_mfma_k<9><<<gC4, b256, 0, stream>>>(U, 256, 8, V, 256, 8, WT, 512, BIAS, W, 256);
    wtx_k<<<dim3((1*128*256 + 128 + 255)/256), b256, 0, stream>>>(
        wp_fc_w, wp_fc_b, nullptr, nullptr, WT, BIAS, 81, 128, 256, 8, 0, 256, 1);
    conv_mfma_k<1><<<gC2, b256, 0, stream>>>(W, 256, 8, nullptr, 0, 0, WT, 256, BIAS, K81, 128);
    softmax81_k<<<72, b256, 0, stream>>>(K81);

    // --- Propagation ---
    xform_k<<<gX4, b256, 0, stream>>>(f1_deep, nullptr, V, 4);
    prop_k<<<gX1, b256, 0, stream>>>(V, K81, U);

    // --- AdaptiveScheduler ---
    xform_k<<<gX1, b256, 0, stream>>>(f1_low, f2_low, W, 1);   // dh -> W
    wtx_k<<<dim3((9*256*256 + 256 + 255)/256), b256, 0, stream>>>(
        sch_c1_w, nullptr, nullptr, nullptr, WT, BIAS, 256, 256, 256, 8, 0, 256, 9);
    borderzero_k<<<73, b256, 0, stream>>>(V, 256);             // V held deeph (pad4)
    conv_mfma_k<9><<<gC4, b256, 0, stream>>>(W, 256, 8, nullptr, 0, 0, WT, 256, BIAS, V, 256);
    wtx_k<<<dim3((9*256*256 + 256 + 255)/256), b256, 0, stream>>>(
        sch_c2_w, sch_c2_b, nullptr, nullptr, WT, BIAS, 256, 256, 256, 8, 0, 256, 9);
    conv_mfma_k<9><<<gC4, b256, 0, stream>>>(V, 256, 8, nullptr, 0, 0, WT, 256, BIAS, F1, 256);
    rowsum_k<<<96, b256, 0, stream>>>(F1, PART);
    dev_k<<<1, b256, 0, stream>>>(PART, sch_fc_w, sch_fc_b, out + NOUT);

    // --- AdaptNet ---
    wtx_k<<<dim3((9*256*512 + 256 + 255)/256), b256, 0, stream>>>(
        ad_c1_w, ad_c1_b, nullptr, nullptr, WT, BIAS, 256, 256, 256, 8, 256, 512, 9);
    conv_mfma_k<9><<<gC4, b256, 0, stream>>>(F2, 256, 8, U, 256, 8, WT, 512, BIAS, W, 256);
    wtx_k<<<dim3((9*256*256 + 256 + 255)/256), b256, 0, stream>>>(
        ad_c2_w, ad_c2_b, nullptr, nullptr, WT, BIAS, 256, 256, 256, 8, 0, 256, 9);
    conv_mfma_k<9><<<gC4, b256, 0, stream>>>(W, 256, 8, nullptr, 0, 0, WT, 256, BIAS, V, 256);
    wtx_k<<<dim3((9*256*256 + 256 + 255)/256), b256, 0, stream>>>(
        ad_c3_w, ad_c3_b, nullptr, nullptr, WT, BIAS, 256, 256, 256, 8, 0, 256, 9);
    conv_mfma_k<9><<<gC4, b256, 0, stream>>>(V, 256, 8, nullptr, 0, 0, WT, 256, BIAS, U, 256);

    // --- reduce_conv2 (1x1 + BN) ---
    wtx_k<<<dim3((1*64*256 + 64 + 255)/256), b256, 0, stream>>>(
        rc_w, rc_b, rc_g, rc_beta, WT, BIAS, 48, 64, 256, 8, 0, 256, 1);
    conv_mfma_k<1><<<gC1, b256, 0, stream>>>(F2, 256, 8, nullptr, 0, 0, WT, 256, BIAS, L48, 64);

    // --- last_conv ---
    wtx_k<<<dim3((9*256*320 + 256 + 255)/256), b256, 0, stream>>>(
        lc1_w, lc1_b, lc1_g, lc1_beta, WT, BIAS, 256, 256, 256, 8, 48, 320, 9);
    conv_mfma_k<9><<<gC4, b256, 0, stream>>>(U, 256, 8, L48, 64, 2, WT, 320, BIAS, V, 256);
    wtx_k<<<dim3((9*256*256 + 256 + 255)/256), b256, 0, stream>>>(
        lc2_w, lc2_b, lc2_g, lc2_beta, WT, BIAS, 256, 256, 256, 8, 0, 256, 9);
    conv_mfma_k<9><<<gC4, b256, 0, stream>>>(V, 256, 8, nullptr, 0, 0, WT, 256, BIAS, W, 256);
    wtx_k<<<dim3((1*64*256 + 64 + 255)/256), b256, 0, stream>>>(
        lc3_w, lc3_b, nullptr, nullptr, WT, BIAS, 19, 64, 256, 8, 0, 256, 1);
    conv_mfma_k<1><<<gC1, b256, 0, stream>>>(W, 256, 8, nullptr, 0, 0, WT, 256, BIAS, F2, 64);

    // --- upsample ---
    upsample_k<<<dim3(NOUT / 256), b256, 0, stream>>>(F2, out);
}

// Round 3
// 897.152 us; speedup vs baseline: 8.5382x; 2.2500x over previous
//
#include <hip/hip_runtime.h>
#include <math.h>

#define HWIMG 18432          // 96*192
#define W2 194               // padded width, pad=1
#define H2 98
#define NPX1 (H2 * W2)       // 19012 padded pixels, pad=1
#define W4 200               // padded width, pad=4
#define H4 104
#define NPX4 (H4 * W4)       // 20800 padded pixels, pad=4
#define NOUT (19 * 384 * 768)

typedef short bf16x8 __attribute__((ext_vector_type(8)));
typedef float f32x16 __attribute__((ext_vector_type(16)));

__device__ __forceinline__ ushort bf16r(float f) {
    union { float f; unsigned u; } a; a.f = f;
    unsigned u = a.u;
    return (ushort)((u + 0x7fffu + ((u >> 16) & 1u)) >> 16);
}
__device__ __forceinline__ float b2f(ushort u) {
    union { unsigned i; float f; } a; a.i = ((unsigned)u) << 16;
    return a.f;
}
__device__ __forceinline__ bf16x8 ld8(const ushort* p) {
    return *reinterpret_cast<const bf16x8*>(p);
}

// ===========================================================================
// Tiled activation layout: act[cb][px][c16], cb = ch/16, px in padded pad=1
// image (NPX1), c16 = ch%16.  A-fragment loads are then fully coalesced:
// lane&31 = px (stride 32B), lane>>5 = k-half (+16B) -> 1KB/wave transaction.
// Weights: wt[tap][kbt][oc][16] -> B-fragments identically coalesced.
// ===========================================================================

// NCHW f32 -> tiled bf16 (full padded range, borders zeroed). optional src-src2.
__global__ __launch_bounds__(256) void xform_t_k(const float* __restrict__ src,
                                                 const float* __restrict__ src2,
                                                 ushort* __restrict__ dst)
{
    const int px = blockIdx.x * 32 + (threadIdx.x & 31);
    const int c8 = (blockIdx.y * 8 + (threadIdx.x >> 5)) * 8;
    if (px >= NPX1) return;
    const int yP = px / W2, xP = px % W2;
    const int y = yP - 1, x = xP - 1;
    ushort v[8];
    if (y >= 0 && y < 96 && x >= 0 && x < 192) {
        const int p = y * 192 + x;
#pragma unroll
        for (int j = 0; j < 8; ++j) {
            float f = src[(size_t)(c8 + j) * HWIMG + p];
            if (src2) f -= src2[(size_t)(c8 + j) * HWIMG + p];
            v[j] = bf16r(f);
        }
    } else {
#pragma unroll
        for (int j = 0; j < 8; ++j) v[j] = 0;
    }
    *reinterpret_cast<uint4*>(dst + ((size_t)(c8 >> 4) * NPX1 + px) * 16 + (c8 & 15))
        = *reinterpret_cast<uint4*>(v);
}

// NCHW f32 -> padded NHWC bf16 (pad=4), for the propagation input only.
__global__ __launch_bounds__(256) void xform_nhwc_k(const float* __restrict__ src,
                                                    ushort* __restrict__ dst)
{
    const int px = blockIdx.x * 8 + (threadIdx.x >> 5);
    const int c8 = (threadIdx.x & 31) * 8;
    if (px >= NPX4) return;
    const int yP = px / W4, xP = px % W4;
    const int y = yP - 4, x = xP - 4;
    ushort v[8];
    if (y >= 0 && y < 96 && x >= 0 && x < 192) {
        const int p = y * 192 + x;
#pragma unroll
        for (int j = 0; j < 8; ++j) v[j] = bf16r(src[(size_t)(c8 + j) * HWIMG + p]);
    } else {
#pragma unroll
        for (int j = 0; j < 8; ++j) v[j] = 0;
    }
    *reinterpret_cast<uint4*>(dst + (size_t)px * 256 + c8) = *reinterpret_cast<uint4*>(v);
}

// Zero the pad=1 border pixels of a tiled buffer with ncb 16-channel blocks.
__global__ __launch_bounds__(256) void borderzero_t_k(ushort* __restrict__ buf, int ncb)
{
    const int idx = blockIdx.x * 256 + threadIdx.x;
    if (idx >= 580 * ncb) return;
    const int pi = idx % 580;
    const int cb = idx / 580;
    int pp;
    if (pi < 194) pp = pi;
    else if (pi < 388) pp = 97 * 194 + (pi - 194);
    else if (pi < 484) pp = (pi - 388 + 1) * 194;
    else pp = (pi - 484 + 1) * 194 + 193;
    uint4 z = {0, 0, 0, 0};
    ushort* p = buf + ((size_t)cb * NPX1 + pp) * 16;
    *reinterpret_cast<uint4*>(p) = z;
    *reinterpret_cast<uint4*>(p + 8) = z;
}

// Weight transform: OIHW f32 -> wt[tap][kbt][ocp][16] bf16 + folded bias f32.
__global__ __launch_bounds__(256) void wtx_k(const float* __restrict__ w,
                                             const float* __restrict__ b,
                                             const float* __restrict__ g,
                                             const float* __restrict__ beta,
                                             ushort* __restrict__ wt,
                                             float* __restrict__ biasout,
                                             int CoutR, int Coutp, int CinR0, int kb0e,
                                             int CinR1, int KBt, int ntaps)
{
    const int idx = blockIdx.x * 256 + threadIdx.x;
    const int total = ntaps * KBt * Coutp * 16;
    const int CinT = CinR0 + CinR1;
    if (idx < total) {
        const int c16 = idx & 15;
        const int oc = (idx >> 4) % Coutp;
        const int kbt = (idx / (16 * Coutp)) % KBt;
        const int tap = idx / (16 * Coutp * KBt);
        const int k = kbt * 16 + c16;
        float val = 0.f;
        if (oc < CoutR) {
            int cit = -1;
            if (k < kb0e) { if (k < CinR0) cit = k; }
            else { const int k1 = k - kb0e; if (k1 < CinR1) cit = CinR0 + k1; }
            if (cit >= 0) {
                val = w[((size_t)oc * CinT + cit) * ntaps + tap];
                if (g) val *= g[oc];
            }
        }
        wt[idx] = bf16r(val);
    } else if (idx < total + Coutp) {
        const int oc = idx - total;
        float v = 0.f;
        if (oc < CoutR) {
            v = b ? b[oc] : 0.f;
            if (g) v = v * g[oc] + beta[oc];
        }
        biasout[oc] = v;
    }
}

// ---------------------------------------------------------------------------
// Implicit-GEMM conv, MFMA 32x32x16 bf16, direct coalesced global loads.
// Block 256 thr = 4 waves; tile 128px (2 rows x 64) x 128 oc; wave 64px x 64oc.
// ---------------------------------------------------------------------------
template<int NTAPS>
__device__ __forceinline__ void conv_accum(
    f32x16 acc[2][2],
    const ushort* __restrict__ act, int KB,
    const ushort* __restrict__ wt, int KBt, int kboff, int Coutp,
    int pxbase, int l31, int klo, int ocb)
{
    const ushort* aB = act + ((size_t)(pxbase + l31)) * 16 + klo;
    const ushort* wB = wt + ((size_t)kboff * Coutp + ocb + l31) * 16 + klo;
    const size_t tapstr = (size_t)KBt * Coutp * 16;

    auto step = [&](int kb) {
        const ushort* a0p = aB + (size_t)kb * NPX1 * 16;
        const ushort* b0p = wB + (size_t)kb * Coutp * 16;
#pragma unroll
        for (int t = 0; t < NTAPS; ++t) {
            const int dy = (NTAPS == 9) ? t / 3 - 1 : 0;
            const int dx = (NTAPS == 9) ? t % 3 - 1 : 0;
            const ptrdiff_t sh = (ptrdiff_t)(dy * W2 + dx) * 16;
            bf16x8 a0 = ld8(a0p + sh);
            bf16x8 a1 = ld8(a0p + sh + 32 * 16);
            bf16x8 b0 = ld8(b0p + (size_t)t * tapstr);
            bf16x8 b1 = ld8(b0p + (size_t)t * tapstr + 32 * 16);
            acc[0][0] = __builtin_amdgcn_mfma_f32_32x32x16_bf16(a0, b0, acc[0][0], 0, 0, 0);
            acc[0][1] = __builtin_amdgcn_mfma_f32_32x32x16_bf16(a0, b1, acc[0][1], 0, 0, 0);
            acc[1][0] = __builtin_amdgcn_mfma_f32_32x32x16_bf16(a1, b0, acc[1][0], 0, 0, 0);
            acc[1][1] = __builtin_amdgcn_mfma_f32_32x32x16_bf16(a1, b1, acc[1][1], 0, 0, 0);
        }
    };

    if constexpr (NTAPS == 1) {
#pragma unroll 4
        for (int kb = 0; kb < KB; ++kb) step(kb);
    } else {
        for (int kb = 0; kb < KB; ++kb) step(kb);
    }
}

template<int NTAPS>
__global__ __launch_bounds__(256, 1) void conv_mfma_k(
    const ushort* __restrict__ in0, int KB0,
    const ushort* __restrict__ in1, int KB1,
    const ushort* __restrict__ wt, int KBt, int Coutp,
    const float* __restrict__ bias,
    ushort* __restrict__ out, int CoutChSt)
{
    const int nblk = gridDim.x;
    const int cpx = nblk >> 3;                       // nblk % 8 == 0
    const int s = ((int)blockIdx.x & 7) * cpx + ((int)blockIdx.x >> 3);
    const int pt = s % 144;
    const int oc0 = (s / 144) << 7;
    const int by = pt / 3, bx = pt % 3;
    const int y0 = by * 2 + 1, x0 = bx * 64 + 1;

    const int lane = threadIdx.x & 63;
    const int wave = threadIdx.x >> 6;
    const int wm = wave & 1, wn = wave >> 1;
    const int l31 = lane & 31, klo = (lane >> 5) * 8;
    const int ocb = oc0 + wn * 64;
    const int pxbase = (y0 + wm) * W2 + x0;

    f32x16 acc[2][2] = {};
    conv_accum<NTAPS>(acc, in0, KB0, wt, KBt, 0, Coutp, pxbase, l31, klo, ocb);
    if (in1)
        conv_accum<NTAPS>(acc, in1, KB1, wt, KBt, KB0, Coutp, pxbase, l31, klo, ocb);

    const int rlo = (lane >> 5) * 4;
#pragma unroll
    for (int j = 0; j < 2; ++j) {
        const int oc = ocb + j * 32 + l31;
        if (ocb + j * 32 + 32 > CoutChSt) continue;  // wave-uniform
        const float bs = bias[oc];
        const size_t obase = (size_t)(oc >> 4) * NPX1 * 16 + (oc & 15);
#pragma unroll
        for (int i = 0; i < 2; ++i) {
#pragma unroll
            for (int r = 0; r < 16; ++r) {
                const int row = (r & 3) + 8 * (r >> 2) + rlo;
                out[obase + (size_t)(pxbase + i * 32 + row) * 16] = bf16r(acc[i][j][r] + bs);
            }
        }
    }
}

// ---------------------------------------------------------------------------
// Softmax over 81 channels (tiled layout, 8 cb blocks), in place, interior px.
// ---------------------------------------------------------------------------
__global__ __launch_bounds__(256) void softmax81_k(ushort* __restrict__ t)
{
    const int p = blockIdx.x * 256 + threadIdx.x;
    if (p >= HWIMG) return;
    const int y = p / 192, x = p % 192;
    const size_t pp = (size_t)(y + 1) * W2 + (x + 1);
    float v[81];
    float m = -1e30f;
#pragma unroll
    for (int k = 0; k < 81; ++k) {
        v[k] = b2f(t[((size_t)(k >> 4) * NPX1 + pp) * 16 + (k & 15)]);
        m = fmaxf(m, v[k]);
    }
    float s = 0.f;
#pragma unroll
    for (int k = 0; k < 81; ++k) { v[k] = __expf(v[k] - m); s += v[k]; }
    const float inv = 1.f / s;
#pragma unroll
    for (int k = 0; k < 81; ++k)
        t[((size_t)(k >> 4) * NPX1 + pp) * 16 + (k & 15)] = bf16r(v[k] * inv);
}

// ---------------------------------------------------------------------------
// Propagation: out[px][c] = sum_k deep[y+dy][x+dx][c] * ker[px][k]
// deep: pad4 NHWC bf16; ker: tiled (8 cb); out: tiled 16 cb, FULL write.
// ---------------------------------------------------------------------------
__global__ __launch_bounds__(256) void prop_k(const ushort* __restrict__ deep,
                                              const ushort* __restrict__ ker,
                                              ushort* __restrict__ out)
{
    __shared__ float kl[8][81];
    const int pxb = blockIdx.x * 8;
    const int t = threadIdx.x;
    for (int i = t; i < 8 * 81; i += 256) {
        const int pp = pxb + i / 81, k = i % 81;
        float kv = 0.f;
        if (pp < NPX1) {
            const int yP = pp / W2, xP = pp % W2;
            if (yP >= 1 && yP <= 96 && xP >= 1 && xP <= 192)
                kv = b2f(ker[((size_t)(k >> 4) * NPX1 + pp) * 16 + (k & 15)]);
        }
        kl[i / 81][k] = kv;
    }
    __syncthreads();
    const int pi = t >> 5;
    const int c8 = (t & 31) * 8;
    const int pp = pxb + pi;
    if (pp >= NPX1) return;
    const int yP = pp / W2, xP = pp % W2;
    ushort* op = out + ((size_t)(c8 >> 4) * NPX1 + pp) * 16 + (c8 & 15);
    if (yP < 1 || yP > 96 || xP < 1 || xP > 192) {
        uint4 z = {0, 0, 0, 0};
        *reinterpret_cast<uint4*>(op) = z;
        return;
    }
    const int y = yP - 1, x = xP - 1;
    float acc[8];
#pragma unroll
    for (int j = 0; j < 8; ++j) acc[j] = 0.f;
    const ushort* dbase = deep + ((size_t)(y + 4) * W4 + (x + 4)) * 256 + c8;
#pragma unroll
    for (int k = 0; k < 81; ++k) {
        const int dy = k / 9 - 4, dx = k % 9 - 4;
        const float kv = kl[pi][k];
        bf16x8 d = ld8(dbase + (ptrdiff_t)(dy * W4 + dx) * 256);
#pragma unroll
        for (int j = 0; j < 8; ++j) acc[j] += b2f((ushort)d[j]) * kv;
    }
    ushort v[8];
#pragma unroll
    for (int j = 0; j < 8; ++j) v[j] = bf16r(acc[j]);
    *reinterpret_cast<uint4*>(op) = *reinterpret_cast<uint4*>(v);
}

// ---------------------------------------------------------------------------
// Per-row channel sums (tiled input): partial[y][c]
// ---------------------------------------------------------------------------
__global__ __launch_bounds__(256) void rowsum_k(const ushort* __restrict__ t,
                                                float* __restrict__ partial)
{
    const int y = blockIdx.x, c = threadIdx.x;
    const size_t base = ((size_t)(c >> 4) * NPX1 + (size_t)(y + 1) * W2 + 1) * 16 + (c & 15);
    float s = 0.f;
    for (int x = 0; x < 192; ++x) s += b2f(t[base + (size_t)x * 16]);
    partial[y * 256 + c] = s;
}

__global__ __launch_bounds__(256) void dev_k(const float* __restrict__ partial,
                                             const float* __restrict__ fcw,
                                             const float* __restrict__ fcb,
                                             float* __restrict__ o)
{
    __shared__ float buf[256];
    const int c = threadIdx.x;
    float s = 0.f;
    for (int y = 0; y < 96; ++y) s += partial[y * 256 + c];
    buf[c] = s * fcw[c];
    __syncthreads();
    for (int st = 128; st > 0; st >>= 1) {
        if (c < st) buf[c] += buf[c + st];
        __syncthreads();
    }
    if (c == 0) o[0] = buf[0] * (1.f / (float)HWIMG) + fcb[0];
}

// ---------------------------------------------------------------------------
// 4x bilinear upsample from tiled bf16 (2 cb blocks, 19 ch used) -> f32 NCHW
// ---------------------------------------------------------------------------
__global__ __launch_bounds__(256) void upsample_k(const ushort* __restrict__ in,
                                                  float* __restrict__ outp)
{
    const int idx = blockIdx.x * 256 + threadIdx.x;
    if (idx >= NOUT) return;
    const int ox = idx % 768;
    const int t = idx / 768;
    const int oy = t % 384;
    const int c = t / 384;

    const float fx = (ox + 0.5f) * 0.25f - 0.5f;
    const float fy = (oy + 0.5f) * 0.25f - 0.5f;
    const int x0 = (int)floorf(fx);
    const int y0 = (int)floorf(fy);
    const float wx = fx - (float)x0;
    const float wy = fy - (float)y0;
    const int x0c = min(max(x0, 0), 191), x1c = min(max(x0 + 1, 0), 191);
    const int y0c = min(max(y0, 0), 95), y1c = min(max(y0 + 1, 0), 95);

    const size_t cb = (size_t)(c >> 4) * NPX1;
    const int c16 = c & 15;
    const float v00 = b2f(in[(cb + (size_t)(y0c + 1) * W2 + (x0c + 1)) * 16 + c16]);
    const float v01 = b2f(in[(cb + (size_t)(y0c + 1) * W2 + (x1c + 1)) * 16 + c16]);
    const float v10 = b2f(in[(cb + (size_t)(y1c + 1) * W2 + (x0c + 1)) * 16 + c16]);
    const float v11 = b2f(in[(cb + (size_t)(y1c + 1) * W2 + (x1c + 1)) * 16 + c16]);
    outp[idx] = (1.f - wy) * ((1.f - wx) * v00 + wx * v01)
              + wy * ((1.f - wx) * v10 + wx * v11);
}

// ---------------------------------------------------------------------------
extern "C" void kernel_launch(void* const* d_in, const int* in_sizes, int n_in,
                              void* d_out, int out_size, void* d_ws, size_t ws_size,
                              hipStream_t stream)
{
    const float* f1_deep = (const float*)d_in[0];
    const float* f1_low  = (const float*)d_in[1];
    const float* f2_low  = (const float*)d_in[2];
    const float* wp_c1_w = (const float*)d_in[3];
    const float* wp_c1_b = (const float*)d_in[4];
    const float* wp_c2_w = (const float*)d_in[5];
    const float* wp_c2_b = (const float*)d_in[6];
    const float* wp_fc_w = (const float*)d_in[7];
    const float* wp_fc_b = (const float*)d_in[8];
    const float* sch_c1_w = (const float*)d_in[9];
    const float* sch_c2_w = (const float*)d_in[11];
    const float* sch_c2_b = (const float*)d_in[12];
    const float* sch_fc_w = (const float*)d_in[13];
    const float* sch_fc_b = (const float*)d_in[14];
    const float* ad_c1_w = (const float*)d_in[15];
    const float* ad_c1_b = (const float*)d_in[16];
    const float* ad_c2_w = (const float*)d_in[17];
    const float* ad_c2_b = (const float*)d_in[18];
    const float* ad_c3_w = (const float*)d_in[19];
    const float* ad_c3_b = (const float*)d_in[20];
    const float* rc_w    = (const float*)d_in[21];
    const float* rc_b    = (const float*)d_in[22];
    const float* rc_g    = (const float*)d_in[23];
    const float* rc_beta = (const float*)d_in[24];
    const float* lc1_w   = (const float*)d_in[25];
    const float* lc1_b   = (const float*)d_in[26];
    const float* lc1_g   = (const float*)d_in[27];
    const float* lc1_beta= (const float*)d_in[28];
    const float* lc2_w   = (const float*)d_in[29];
    const float* lc2_b   = (const float*)d_in[30];
    const float* lc2_g   = (const float*)d_in[31];
    const float* lc2_beta= (const float*)d_in[32];
    const float* lc3_w   = (const float*)d_in[33];
    const float* lc3_b   = (const float*)d_in[34];

    float* out = (float*)d_out;
    char* ws = (char*)d_ws;

    const size_t CBB = (size_t)NPX1 * 16 * 2 * 16;   // 16-cb tiled buffer: 9,734,144 B
    const size_t BUF0SZ = (size_t)NPX4 * 256 * 2;    // 10,649,600 B
    ushort* F1t  = (ushort*)(ws);                    // also D4 (deep pad4) later
    ushort* D4   = F1t;
    ushort* F2t  = (ushort*)(ws + BUF0SZ);
    ushort* DIFF = (ushort*)(ws + BUF0SZ + CBB);
    ushort* U    = (ushort*)(ws + BUF0SZ + 2 * CBB);
    ushort* V    = (ushort*)(ws + BUF0SZ + 3 * CBB);
    ushort* W    = (ushort*)(ws + BUF0SZ + 4 * CBB);
    ushort* WT   = (ushort*)(ws + BUF0SZ + 5 * CBB);
    float* BIAS  = (float*)((char*)WT + (size_t)9 * 32 * 256 * 16 * 2);
    float* PART  = BIAS + 256;
    ushort* K81  = V;     // lives steps 6..9 (V free in that window)
    ushort* L48  = DIFF;  // lives steps 15..16 (DIFF free)
    ushort* O19  = F2t;   // lives steps 18..19 (F2t free)

    const dim3 b256(256);
    const dim3 gXT(595, 4);
    const dim3 gC2(288), gC1(144);

    // 1. input transforms
    xform_t_k<<<gXT, b256, 0, stream>>>(f1_low, nullptr, F1t);
    xform_t_k<<<gXT, b256, 0, stream>>>(f2_low, nullptr, F2t);
    xform_t_k<<<gXT, b256, 0, stream>>>(f1_low, f2_low, DIFF);
    // 2. zero borders of conv-output buffers (written interior-only afterwards)
    borderzero_t_k<<<(580 * 16 + 255) / 256, b256, 0, stream>>>(U, 16);
    borderzero_t_k<<<(580 * 16 + 255) / 256, b256, 0, stream>>>(V, 16);
    borderzero_t_k<<<(580 * 16 + 255) / 256, b256, 0, stream>>>(W, 16);

    // 3-4. WeightPredictor conv1 (shared weights) on both low features
    wtx_k<<<(9 * 16 * 256 * 16 + 256 + 255) / 256, b256, 0, stream>>>(
        wp_c1_w, wp_c1_b, nullptr, nullptr, WT, BIAS, 256, 256, 256, 256, 0, 16, 9);
    conv_mfma_k<9><<<gC2, b256, 0, stream>>>(F1t, 16, nullptr, 0, WT, 16, 256, BIAS, U, 256);
    conv_mfma_k<9><<<gC2, b256, 0, stream>>>(F2t, 16, nullptr, 0, WT, 16, 256, BIAS, V, 256);
    // 5. conv2 on concat
    wtx_k<<<(9 * 32 * 256 * 16 + 256 + 255) / 256, b256, 0, stream>>>(
        wp_c2_w, wp_c2_b, nullptr, nullptr, WT, BIAS, 256, 256, 256, 256, 256, 32, 9);
    conv_mfma_k<9><<<gC2, b256, 0, stream>>>(U, 16, V, 16, WT, 32, 256, BIAS, W, 256);
    // 6-7. fc (1x1) -> 81ch kernel + softmax
    wtx_k<<<(1 * 16 * 128 * 16 + 128 + 255) / 256, b256, 0, stream>>>(
        wp_fc_w, wp_fc_b, nullptr, nullptr, WT, BIAS, 81, 128, 256, 256, 0, 16, 1);
    conv_mfma_k<1><<<gC1, b256, 0, stream>>>(W, 16, nullptr, 0, WT, 16, 128, BIAS, K81, 128);
    softmax81_k<<<72, b256, 0, stream>>>(K81);

    // 8-9. propagation
    xform_nhwc_k<<<2600, b256, 0, stream>>>(f1_deep, D4);
    prop_k<<<2377, b256, 0, stream>>>(D4, K81, U);

    // 10-11. AdaptiveScheduler (bias of conv1 cancels in the difference)
    wtx_k<<<(9 * 16 * 256 * 16 + 256 + 255) / 256, b256, 0, stream>>>(
        sch_c1_w, nullptr, nullptr, nullptr, WT, BIAS, 256, 256, 256, 256, 0, 16, 9);
    conv_mfma_k<9><<<gC2, b256, 0, stream>>>(DIFF, 16, nullptr, 0, WT, 16, 256, BIAS, V, 256);
    wtx_k<<<(9 * 16 * 256 * 16 + 256 + 255) / 256, b256, 0, stream>>>(
        sch_c2_w, sch_c2_b, nullptr, nullptr, WT, BIAS, 256, 256, 256, 256, 0, 16, 9);
    conv_mfma_k<9><<<gC2, b256, 0, stream>>>(V, 16, nullptr, 0, WT, 16, 256, BIAS, W, 256);
    rowsum_k<<<96, b256, 0, stream>>>(W, PART);
    dev_k<<<1, b256, 0, stream>>>(PART, sch_fc_w, sch_fc_b, out + NOUT);

    // 12-14. AdaptNet
    wtx_k<<<(9 * 32 * 256 * 16 + 256 + 255) / 256, b256, 0, stream>>>(
        ad_c1_w, ad_c1_b, nullptr, nullptr, WT, BIAS, 256, 256, 256, 256, 256, 32, 9);
    conv_mfma_k<9><<<gC2, b256, 0, stream>>>(F2t, 16, U, 16, WT, 32, 256, BIAS, DIFF, 256);
    wtx_k<<<(9 * 16 * 256 * 16 + 256 + 255) / 256, b256, 0, stream>>>(
        ad_c2_w, ad_c2_b, nullptr, nullptr, WT, BIAS, 256, 256, 256, 256, 0, 16, 9);
    conv_mfma_k<9><<<gC2, b256, 0, stream>>>(DIFF, 16, nullptr, 0, WT, 16, 256, BIAS, V, 256);
    wtx_k<<<(9 * 16 * 256 * 16 + 256 + 255) / 256, b256, 0, stream>>>(
        ad_c3_w, ad_c3_b, nullptr, nullptr, WT, BIAS, 256, 256, 256, 256, 0, 16, 9);
    conv_mfma_k<9><<<gC2, b256, 0, stream>>>(V, 16, nullptr, 0, WT, 16, 256, BIAS, W, 256);

    // 15. reduce_conv2 (1x1 + BN) -> L48 (zero its borders first; overlays DIFF)
    borderzero_t_k<<<(580 * 4 + 255) / 256, b256, 0, stream>>>(L48, 4);
    wtx_k<<<(1 * 16 * 128 * 16 + 128 + 255) / 256, b256, 0, stream>>>(
        rc_w, rc_b, rc_g, rc_beta, WT, BIAS, 48, 128, 256, 256, 0, 16, 1);
    conv_mfma_k<1><<<gC1, b256, 0, stream>>>(F2t, 16, nullptr, 0, WT, 16, 128, BIAS, L48, 64);

    // 16-18. last_conv
    wtx_k<<<(9 * 20 * 256 * 16 + 256 + 255) / 256, b256, 0, stream>>>(
        lc1_w, lc1_b, lc1_g, lc1_beta, WT, BIAS, 256, 256, 256, 256, 48, 20, 9);
    conv_mfma_k<9><<<gC2, b256, 0, stream>>>(W, 16, L48, 4, WT, 20, 256, BIAS, U, 256);
    wtx_k<<<(9 * 16 * 256 * 16 + 256 + 255) / 256, b256, 0, stream>>>(
        lc2_w, lc2_b, lc2_g, lc2_beta, WT, BIAS, 256, 256, 256, 256, 0, 16, 9);
    conv_mfma_k<9><<<gC2, b256, 0, stream>>>(U, 16, nullptr, 0, WT, 16, 256, BIAS, V, 256);
    wtx_k<<<(1 * 16 * 128 * 16 + 128 + 255) / 256, b256, 0, stream>>>(
        lc3_w, lc3_b, nullptr, nullptr, WT, BIAS, 19, 128, 256, 256, 0, 16, 1);
    conv_mfma_k<1><<<gC1, b256, 0, stream>>>(V, 16, nullptr, 0, WT, 16, 128, BIAS, O19, 32);

    // 19. upsample
    upsample_k<<<(NOUT + 255) / 256, b256, 0, stream>>>(O19, out);
}

// Round 4
// 613.861 us; speedup vs baseline: 12.4785x; 1.4615x over previous
//
#include <hip/hip_runtime.h>
#include <math.h>

#define HWIMG 18432          // 96*192
#define W2 194               // padded width, pad=1
#define H2 98
#define NPX1 (H2 * W2)       // 19012 padded pixels, pad=1
#define W4 200               // padded width, pad=4
#define H4 104
#define NPX4 (H4 * W4)       // 20800 padded pixels, pad=4
#define NOUT (19 * 384 * 768)

typedef short bf16x8 __attribute__((ext_vector_type(8)));
typedef float f32x16 __attribute__((ext_vector_type(16)));

__device__ __forceinline__ ushort bf16r(float f) {
    union { float f; unsigned u; } a; a.f = f;
    unsigned u = a.u;
    return (ushort)((u + 0x7fffu + ((u >> 16) & 1u)) >> 16);
}
__device__ __forceinline__ float b2f(ushort u) {
    union { unsigned i; float f; } a; a.i = ((unsigned)u) << 16;
    return a.f;
}
__device__ __forceinline__ bf16x8 ld8(const ushort* p) {
    return *reinterpret_cast<const bf16x8*>(p);
}

// ===========================================================================
// Tiled activation layout: act[cb][px][c16]  (cb = ch/16, px in padded pad=1
// image, c16 = ch%16).  A-fragments and B-fragments are single fully-coalesced
// 1KB wave loads. Weights: wt[kb][tap][oc][16] -> B address linear in step.
// ===========================================================================

// NCHW f32 -> tiled bf16 (full padded range, borders zeroed). optional src-src2.
__global__ __launch_bounds__(256) void xform_t_k(const float* __restrict__ src,
                                                 const float* __restrict__ src2,
                                                 ushort* __restrict__ dst)
{
    const int px = blockIdx.x * 32 + (threadIdx.x & 31);
    const int c8 = (blockIdx.y * 8 + (threadIdx.x >> 5)) * 8;
    if (px >= NPX1) return;
    const int yP = px / W2, xP = px % W2;
    const int y = yP - 1, x = xP - 1;
    ushort v[8];
    if (y >= 0 && y < 96 && x >= 0 && x < 192) {
        const int p = y * 192 + x;
#pragma unroll
        for (int j = 0; j < 8; ++j) {
            float f = src[(size_t)(c8 + j) * HWIMG + p];
            if (src2) f -= src2[(size_t)(c8 + j) * HWIMG + p];
            v[j] = bf16r(f);
        }
    } else {
#pragma unroll
        for (int j = 0; j < 8; ++j) v[j] = 0;
    }
    *reinterpret_cast<uint4*>(dst + ((size_t)(c8 >> 4) * NPX1 + px) * 16 + (c8 & 15))
        = *reinterpret_cast<uint4*>(v);
}

// NCHW f32 -> padded NHWC bf16 (pad=4), for the propagation input only.
__global__ __launch_bounds__(256) void xform_nhwc_k(const float* __restrict__ src,
                                                    ushort* __restrict__ dst)
{
    const int px = blockIdx.x * 8 + (threadIdx.x >> 5);
    const int c8 = (threadIdx.x & 31) * 8;
    if (px >= NPX4) return;
    const int yP = px / W4, xP = px % W4;
    const int y = yP - 4, x = xP - 4;
    ushort v[8];
    if (y >= 0 && y < 96 && x >= 0 && x < 192) {
        const int p = y * 192 + x;
#pragma unroll
        for (int j = 0; j < 8; ++j) v[j] = bf16r(src[(size_t)(c8 + j) * HWIMG + p]);
    } else {
#pragma unroll
        for (int j = 0; j < 8; ++j) v[j] = 0;
    }
    *reinterpret_cast<uint4*>(dst + (size_t)px * 256 + c8) = *reinterpret_cast<uint4*>(v);
}

// Zero the pad=1 border pixels of a tiled buffer with ncb 16-channel blocks.
__global__ __launch_bounds__(256) void borderzero_t_k(ushort* __restrict__ buf, int ncb)
{
    const int idx = blockIdx.x * 256 + threadIdx.x;
    if (idx >= 580 * ncb) return;
    const int pi = idx % 580;
    const int cb = idx / 580;
    int pp;
    if (pi < 194) pp = pi;
    else if (pi < 388) pp = 97 * 194 + (pi - 194);
    else if (pi < 484) pp = (pi - 388 + 1) * 194;
    else pp = (pi - 484 + 1) * 194 + 193;
    uint4 z = {0, 0, 0, 0};
    ushort* p = buf + ((size_t)cb * NPX1 + pp) * 16;
    *reinterpret_cast<uint4*>(p) = z;
    *reinterpret_cast<uint4*>(p + 8) = z;
}

// Weight transform: OIHW f32 -> wt[kbt][tap][ocp][16] bf16 + folded bias f32.
__global__ __launch_bounds__(256) void wtx_k(const float* __restrict__ w,
                                             const float* __restrict__ b,
                                             const float* __restrict__ g,
                                             const float* __restrict__ beta,
                                             ushort* __restrict__ wt,
                                             float* __restrict__ biasout,
                                             int CoutR, int Coutp, int CinR0, int kb0e,
                                             int CinR1, int KBt, int ntaps)
{
    const int idx = blockIdx.x * 256 + threadIdx.x;
    const int total = ntaps * KBt * Coutp * 16;
    const int CinT = CinR0 + CinR1;
    if (idx < total) {
        const int c16 = idx & 15;
        const int oc = (idx >> 4) % Coutp;
        const int r2 = idx / (16 * Coutp);
        const int tap = r2 % ntaps;
        const int kbt = r2 / ntaps;
        const int k = kbt * 16 + c16;
        float val = 0.f;
        if (oc < CoutR) {
            int cit = -1;
            if (k < kb0e) { if (k < CinR0) cit = k; }
            else { const int k1 = k - kb0e; if (k1 < CinR1) cit = CinR0 + k1; }
            if (cit >= 0) {
                val = w[((size_t)oc * CinT + cit) * ntaps + tap];
                if (g) val *= g[oc];
            }
        }
        wt[idx] = bf16r(val);
    } else if (idx < total + Coutp) {
        const int oc = idx - total;
        float v = 0.f;
        if (oc < CoutR) {
            v = b ? b[oc] : 0.f;
            if (g) v = v * g[oc] + beta[oc];
        }
        biasout[oc] = v;
    }
}

// ---------------------------------------------------------------------------
// Implicit-GEMM conv, MFMA 32x32x16 bf16, 8-slot software-pipelined register
// prefetch. Block 128 thr = 2 waves; block tile 64px x 128oc; wave 64px x 64oc.
// Step s = kb*NTAPS + tap: loads {a0,a1,b0,b1}, 4 MFMAs. nsteps % 8 == 0.
// ---------------------------------------------------------------------------
struct Frag { bf16x8 a0, a1, b0, b1; };

template<int NTAPS>
__device__ __forceinline__ void ldstep(Frag& f, int t,
    const ushort* __restrict__ in0p, const ushort* __restrict__ in1p, int KB0,
    const ushort* __restrict__ wp, int bstride)
{
    int kb, tap;
    if constexpr (NTAPS == 9) { kb = t / 9; tap = t - kb * 9; }
    else { kb = t; tap = 0; }
    const ushort* ab = ((kb < KB0) ? in0p : in1p) + (size_t)kb * (NPX1 * 16);
    if constexpr (NTAPS == 9)
        ab += ((tap / 3) * W2 + (tap % 3)) * 16 - ((W2 + 1) * 16);
    f.a0 = ld8(ab);
    f.a1 = ld8(ab + 512);
    const ushort* bp = wp + (size_t)t * bstride;
    f.b0 = ld8(bp);
    f.b1 = ld8(bp + 512);
}

template<int NTAPS>
__global__ __launch_bounds__(128) void conv_mfma_k(
    const ushort* __restrict__ in0, int KB0,
    const ushort* __restrict__ in1, int KB1,
    const ushort* __restrict__ wt, int Coutp,
    const float* __restrict__ bias,
    ushort* __restrict__ out, int CoutChSt)
{
    const int nblk = gridDim.x;
    const int cpx = nblk >> 3;                       // nblk % 8 == 0
    const int sblk = ((int)blockIdx.x & 7) * cpx + ((int)blockIdx.x >> 3);
    const int pt = sblk % 288;
    const int ocblk = sblk / 288;
    const int row = 1 + pt / 3;
    const int x0 = (pt % 3) * 64 + 1;

    const int lane = threadIdx.x & 63;
    const int wave = threadIdx.x >> 6;               // 0..1
    const int l31 = lane & 31, klo = (lane >> 5) * 8;
    const int ocb = ocblk * 128 + wave * 64;
    const int pxbase = row * W2 + x0;

    const size_t pxoff = (size_t)(pxbase + l31) * 16 + klo;
    const ushort* in0p = in0 + pxoff;
    const ushort* in1p = (in1 ? in1 : in0) + pxoff - (size_t)KB0 * (NPX1 * 16);
    const ushort* wp = wt + (size_t)(ocb + l31) * 16 + klo;
    const int bstride = Coutp * 16;
    const int nsteps = (KB0 + KB1) * NTAPS;          // always % 8 == 0
    const int tmax = nsteps - 1;

    f32x16 c00 = {}, c01 = {}, c10 = {}, c11 = {};

    Frag f0, f1, f2, f3, f4, f5, f6, f7;
    ldstep<NTAPS>(f0, 0, in0p, in1p, KB0, wp, bstride);
    ldstep<NTAPS>(f1, 1, in0p, in1p, KB0, wp, bstride);
    ldstep<NTAPS>(f2, 2, in0p, in1p, KB0, wp, bstride);
    ldstep<NTAPS>(f3, 3, in0p, in1p, KB0, wp, bstride);
    ldstep<NTAPS>(f4, 4, in0p, in1p, KB0, wp, bstride);
    ldstep<NTAPS>(f5, 5, in0p, in1p, KB0, wp, bstride);
    ldstep<NTAPS>(f6, 6, in0p, in1p, KB0, wp, bstride);

#define MSTEP(F)                                                              \
    c00 = __builtin_amdgcn_mfma_f32_32x32x16_bf16(F.a0, F.b0, c00, 0, 0, 0);  \
    c01 = __builtin_amdgcn_mfma_f32_32x32x16_bf16(F.a0, F.b1, c01, 0, 0, 0);  \
    c10 = __builtin_amdgcn_mfma_f32_32x32x16_bf16(F.a1, F.b0, c10, 0, 0, 0);  \
    c11 = __builtin_amdgcn_mfma_f32_32x32x16_bf16(F.a1, F.b1, c11, 0, 0, 0);

    for (int s = 0; s < nsteps; s += 8) {
        ldstep<NTAPS>(f7, min(s + 7,  tmax), in0p, in1p, KB0, wp, bstride); MSTEP(f0);
        ldstep<NTAPS>(f0, min(s + 8,  tmax), in0p, in1p, KB0, wp, bstride); MSTEP(f1);
        ldstep<NTAPS>(f1, min(s + 9,  tmax), in0p, in1p, KB0, wp, bstride); MSTEP(f2);
        ldstep<NTAPS>(f2, min(s + 10, tmax), in0p, in1p, KB0, wp, bstride); MSTEP(f3);
        ldstep<NTAPS>(f3, min(s + 11, tmax), in0p, in1p, KB0, wp, bstride); MSTEP(f4);
        ldstep<NTAPS>(f4, min(s + 12, tmax), in0p, in1p, KB0, wp, bstride); MSTEP(f5);
        ldstep<NTAPS>(f5, min(s + 13, tmax), in0p, in1p, KB0, wp, bstride); MSTEP(f6);
        ldstep<NTAPS>(f6, min(s + 14, tmax), in0p, in1p, KB0, wp, bstride); MSTEP(f7);
    }
#undef MSTEP

    const int rlo = (lane >> 5) * 4;
#pragma unroll
    for (int j = 0; j < 2; ++j) {
        if (ocb + j * 32 + 32 > CoutChSt) continue;  // wave-uniform
        const int oc = ocb + j * 32 + l31;
        const float bs = bias[oc];
        const size_t obase = (size_t)(oc >> 4) * ((size_t)NPX1 * 16) + (oc & 15);
        const f32x16 v0 = j ? c01 : c00;
        const f32x16 v1 = j ? c11 : c10;
#pragma unroll
        for (int r = 0; r < 16; ++r) {
            const int rw = (r & 3) + 8 * (r >> 2) + rlo;
            out[obase + (size_t)(pxbase + rw) * 16] = bf16r(v0[r] + bs);
            out[obase + (size_t)(pxbase + 32 + rw) * 16] = bf16r(v1[r] + bs);
        }
    }
}

// ---------------------------------------------------------------------------
// Softmax over 81 channels (tiled layout), in place, interior pixels.
// ---------------------------------------------------------------------------
__global__ __launch_bounds__(256) void softmax81_k(ushort* __restrict__ t)
{
    const int p = blockIdx.x * 256 + threadIdx.x;
    if (p >= HWIMG) return;
    const int y = p / 192, x = p % 192;
    const size_t pp = (size_t)(y + 1) * W2 + (x + 1);
    float v[81];
    float m = -1e30f;
#pragma unroll
    for (int k = 0; k < 81; ++k) {
        v[k] = b2f(t[((size_t)(k >> 4) * NPX1 + pp) * 16 + (k & 15)]);
        m = fmaxf(m, v[k]);
    }
    float s = 0.f;
#pragma unroll
    for (int k = 0; k < 81; ++k) { v[k] = __expf(v[k] - m); s += v[k]; }
    const float inv = 1.f / s;
#pragma unroll
    for (int k = 0; k < 81; ++k)
        t[((size_t)(k >> 4) * NPX1 + pp) * 16 + (k & 15)] = bf16r(v[k] * inv);
}

// ---------------------------------------------------------------------------
// Propagation: out[px][c] = sum_k deep[y+dy][x+dx][c] * ker[px][k]
// deep: pad4 NHWC bf16; ker: tiled (6 cb used of 8); out: tiled, FULL write.
// ---------------------------------------------------------------------------
__global__ __launch_bounds__(256) void prop_k(const ushort* __restrict__ deep,
                                              const ushort* __restrict__ ker,
                                              ushort* __restrict__ out)
{
    __shared__ float kl[8][81];
    const int pxb = blockIdx.x * 8;
    const int t = threadIdx.x;
    for (int i = t; i < 8 * 81; i += 256) {
        const int pp = pxb + i / 81, k = i % 81;
        float kv = 0.f;
        if (pp < NPX1) {
            const int yP = pp / W2, xP = pp % W2;
            if (yP >= 1 && yP <= 96 && xP >= 1 && xP <= 192)
                kv = b2f(ker[((size_t)(k >> 4) * NPX1 + pp) * 16 + (k & 15)]);
        }
        kl[i / 81][k] = kv;
    }
    __syncthreads();
    const int pi = t >> 5;
    const int c8 = (t & 31) * 8;
    const int pp = pxb + pi;
    if (pp >= NPX1) return;
    const int yP = pp / W2, xP = pp % W2;
    ushort* op = out + ((size_t)(c8 >> 4) * NPX1 + pp) * 16 + (c8 & 15);
    if (yP < 1 || yP > 96 || xP < 1 || xP > 192) {
        uint4 z = {0, 0, 0, 0};
        *reinterpret_cast<uint4*>(op) = z;
        return;
    }
    const int y = yP - 1, x = xP - 1;
    float acc[8];
#pragma unroll
    for (int j = 0; j < 8; ++j) acc[j] = 0.f;
    const ushort* dbase = deep + ((size_t)(y + 4) * W4 + (x + 4)) * 256 + c8;
#pragma unroll
    for (int k = 0; k < 81; ++k) {
        const int dy = k / 9 - 4, dx = k % 9 - 4;
        const float kv = kl[pi][k];
        bf16x8 d = ld8(dbase + (ptrdiff_t)(dy * W4 + dx) * 256);
#pragma unroll
        for (int j = 0; j < 8; ++j) acc[j] += b2f((ushort)d[j]) * kv;
    }
    ushort v[8];
#pragma unroll
    for (int j = 0; j < 8; ++j) v[j] = bf16r(acc[j]);
    *reinterpret_cast<uint4*>(op) = *reinterpret_cast<uint4*>(v);
}

// ---------------------------------------------------------------------------
// Per-row channel sums (tiled input): partial[y][c]
// ---------------------------------------------------------------------------
__global__ __launch_bounds__(256) void rowsum_k(const ushort* __restrict__ t,
                                                float* __restrict__ partial)
{
    const int y = blockIdx.x, c = threadIdx.x;
    const size_t base = ((size_t)(c >> 4) * NPX1 + (size_t)(y + 1) * W2 + 1) * 16 + (c & 15);
    float s = 0.f;
    for (int x = 0; x < 192; ++x) s += b2f(t[base + (size_t)x * 16]);
    partial[y * 256 + c] = s;
}

__global__ __launch_bounds__(256) void dev_k(const float* __restrict__ partial,
                                             const float* __restrict__ fcw,
                                             const float* __restrict__ fcb,
                                             float* __restrict__ o)
{
    __shared__ float buf[256];
    const int c = threadIdx.x;
    float s = 0.f;
    for (int y = 0; y < 96; ++y) s += partial[y * 256 + c];
    buf[c] = s * fcw[c];
    __syncthreads();
    for (int st = 128; st > 0; st >>= 1) {
        if (c < st) buf[c] += buf[c + st];
        __syncthreads();
    }
    if (c == 0) o[0] = buf[0] * (1.f / (float)HWIMG) + fcb[0];
}

// ---------------------------------------------------------------------------
// 4x bilinear upsample from tiled bf16 (19 ch used) -> f32 NCHW
// ---------------------------------------------------------------------------
__global__ __launch_bounds__(256) void upsample_k(const ushort* __restrict__ in,
                                                  float* __restrict__ outp)
{
    const int idx = blockIdx.x * 256 + threadIdx.x;
    if (idx >= NOUT) return;
    const int ox = idx % 768;
    const int t = idx / 768;
    const int oy = t % 384;
    const int c = t / 384;

    const float fx = (ox + 0.5f) * 0.25f - 0.5f;
    const float fy = (oy + 0.5f) * 0.25f - 0.5f;
    const int x0 = (int)floorf(fx);
    const int y0 = (int)floorf(fy);
    const float wx = fx - (float)x0;
    const float wy = fy - (float)y0;
    const int x0c = min(max(x0, 0), 191), x1c = min(max(x0 + 1, 0), 191);
    const int y0c = min(max(y0, 0), 95), y1c = min(max(y0 + 1, 0), 95);

    const size_t cb = (size_t)(c >> 4) * NPX1;
    const int c16 = c & 15;
    const float v00 = b2f(in[(cb + (size_t)(y0c + 1) * W2 + (x0c + 1)) * 16 + c16]);
    const float v01 = b2f(in[(cb + (size_t)(y0c + 1) * W2 + (x1c + 1)) * 16 + c16]);
    const float v10 = b2f(in[(cb + (size_t)(y1c + 1) * W2 + (x0c + 1)) * 16 + c16]);
    const float v11 = b2f(in[(cb + (size_t)(y1c + 1) * W2 + (x1c + 1)) * 16 + c16]);
    outp[idx] = (1.f - wy) * ((1.f - wx) * v00 + wx * v01)
              + wy * ((1.f - wx) * v10 + wx * v11);
}

// ---------------------------------------------------------------------------
extern "C" void kernel_launch(void* const* d_in, const int* in_sizes, int n_in,
                              void* d_out, int out_size, void* d_ws, size_t ws_size,
                              hipStream_t stream)
{
    const float* f1_deep = (const float*)d_in[0];
    const float* f1_low  = (const float*)d_in[1];
    const float* f2_low  = (const float*)d_in[2];
    const float* wp_c1_w = (const float*)d_in[3];
    const float* wp_c1_b = (const float*)d_in[4];
    const float* wp_c2_w = (const float*)d_in[5];
    const float* wp_c2_b = (const float*)d_in[6];
    const float* wp_fc_w = (const float*)d_in[7];
    const float* wp_fc_b = (const float*)d_in[8];
    const float* sch_c1_w = (const float*)d_in[9];
    const float* sch_c2_w = (const float*)d_in[11];
    const float* sch_c2_b = (const float*)d_in[12];
    const float* sch_fc_w = (const float*)d_in[13];
    const float* sch_fc_b = (const float*)d_in[14];
    const float* ad_c1_w = (const float*)d_in[15];
    const float* ad_c1_b = (const float*)d_in[16];
    const float* ad_c2_w = (const float*)d_in[17];
    const float* ad_c2_b = (const float*)d_in[18];
    const float* ad_c3_w = (const float*)d_in[19];
    const float* ad_c3_b = (const float*)d_in[20];
    const float* rc_w    = (const float*)d_in[21];
    const float* rc_b    = (const float*)d_in[22];
    const float* rc_g    = (const float*)d_in[23];
    const float* rc_beta = (const float*)d_in[24];
    const float* lc1_w   = (const float*)d_in[25];
    const float* lc1_b   = (const float*)d_in[26];
    const float* lc1_g   = (const float*)d_in[27];
    const float* lc1_beta= (const float*)d_in[28];
    const float* lc2_w   = (const float*)d_in[29];
    const float* lc2_b   = (const float*)d_in[30];
    const float* lc2_g   = (const float*)d_in[31];
    const float* lc2_beta= (const float*)d_in[32];
    const float* lc3_w   = (const float*)d_in[33];
    const float* lc3_b   = (const float*)d_in[34];

    float* out = (float*)d_out;
    char* ws = (char*)d_ws;

    const size_t CBB = (size_t)NPX1 * 16 * 2 * 16;   // 16-cb tiled buffer: 9,734,144 B
    const size_t BUF0SZ = (size_t)NPX4 * 256 * 2;    // 10,649,600 B
    ushort* F1t  = (ushort*)(ws);                    // also D4 (deep pad4) later
    ushort* D4   = F1t;
    ushort* F2t  = (ushort*)(ws + BUF0SZ);
    ushort* DIFF = (ushort*)(ws + BUF0SZ + CBB);
    ushort* U    = (ushort*)(ws + BUF0SZ + 2 * CBB);
    ushort* V    = (ushort*)(ws + BUF0SZ + 3 * CBB);
    ushort* W    = (ushort*)(ws + BUF0SZ + 4 * CBB);
    ushort* WT   = (ushort*)(ws + BUF0SZ + 5 * CBB);
    float* BIAS  = (float*)((char*)WT + (size_t)9 * 32 * 256 * 16 * 2);
    float* PART  = BIAS + 256;
    ushort* K81  = V;     // lives steps 6..9 (V free in that window)
    ushort* L48  = DIFF;  // lives steps 15..16 (DIFF free)
    ushort* O19  = F2t;   // lives steps 18..19 (F2t free)

    const dim3 b256(256), b128(128);
    const dim3 gXT(595, 4);
    const dim3 gC2(576), gC1(288);

    // 1. input transforms
    xform_t_k<<<gXT, b256, 0, stream>>>(f1_low, nullptr, F1t);
    xform_t_k<<<gXT, b256, 0, stream>>>(f2_low, nullptr, F2t);
    xform_t_k<<<gXT, b256, 0, stream>>>(f1_low, f2_low, DIFF);
    // 2. zero borders of conv-output buffers (written interior-only afterwards)
    borderzero_t_k<<<(580 * 16 + 255) / 256, b256, 0, stream>>>(U, 16);
    borderzero_t_k<<<(580 * 16 + 255) / 256, b256, 0, stream>>>(V, 16);
    borderzero_t_k<<<(580 * 16 + 255) / 256, b256, 0, stream>>>(W, 16);

    // 3-4. WeightPredictor conv1 (shared weights) on both low features
    wtx_k<<<(9 * 16 * 256 * 16 + 256 + 255) / 256, b256, 0, stream>>>(
        wp_c1_w, wp_c1_b, nullptr, nullptr, WT, BIAS, 256, 256, 256, 256, 0, 16, 9);
    conv_mfma_k<9><<<gC2, b128, 0, stream>>>(F1t, 16, nullptr, 0, WT, 256, BIAS, U, 256);
    conv_mfma_k<9><<<gC2, b128, 0, stream>>>(F2t, 16, nullptr, 0, WT, 256, BIAS, V, 256);
    // 5. conv2 on concat
    wtx_k<<<(9 * 32 * 256 * 16 + 256 + 255) / 256, b256, 0, stream>>>(
        wp_c2_w, wp_c2_b, nullptr, nullptr, WT, BIAS, 256, 256, 256, 256, 256, 32, 9);
    conv_mfma_k<9><<<gC2, b128, 0, stream>>>(U, 16, V, 16, WT, 256, BIAS, W, 256);
    // 6-7. fc (1x1) -> 81ch kernel + softmax
    wtx_k<<<(1 * 16 * 128 * 16 + 128 + 255) / 256, b256, 0, stream>>>(
        wp_fc_w, wp_fc_b, nullptr, nullptr, WT, BIAS, 81, 128, 256, 256, 0, 16, 1);
    conv_mfma_k<1><<<gC1, b128, 0, stream>>>(W, 16, nullptr, 0, WT, 128, BIAS, K81, 128);
    softmax81_k<<<72, b256, 0, stream>>>(K81);

    // 8-9. propagation
    xform_nhwc_k<<<2600, b256, 0, stream>>>(f1_deep, D4);
    prop_k<<<2377, b256, 0, stream>>>(D4, K81, U);

    // 10-11. AdaptiveScheduler (bias of conv1 cancels in the difference)
    wtx_k<<<(9 * 16 * 256 * 16 + 256 + 255) / 256, b256, 0, stream>>>(
        sch_c1_w, nullptr, nullptr, nullptr, WT, BIAS, 256, 256, 256, 256, 0, 16, 9);
    conv_mfma_k<9><<<gC2, b128, 0, stream>>>(DIFF, 16, nullptr, 0, WT, 256, BIAS, V, 256);
    wtx_k<<<(9 * 16 * 256 * 16 + 256 + 255) / 256, b256, 0, stream>>>(
        sch_c2_w, sch_c2_b, nullptr, nullptr, WT, BIAS, 256, 256, 256, 256, 0, 16, 9);
    conv_mfma_k<9><<<gC2, b128, 0, stream>>>(V, 16, nullptr, 0, WT, 256, BIAS, W, 256);
    rowsum_k<<<96, b256, 0, stream>>>(W, PART);
    dev_k<<<1, b256, 0, stream>>>(PART, sch_fc_w, sch_fc_b, out + NOUT);

    // 12-14. AdaptNet
    wtx_k<<<(9 * 32 * 256 * 16 + 256 + 255) / 256, b256, 0, stream>>>(
        ad_c1_w, ad_c1_b, nullptr, nullptr, WT, BIAS, 256, 256, 256, 256, 256, 32, 9);
    conv_mfma_k<9><<<gC2, b128, 0, stream>>>(F2t, 16, U, 16, WT, 256, BIAS, DIFF, 256);
    wtx_k<<<(9 * 16 * 256 * 16 + 256 + 255) / 256, b256, 0, stream>>>(
        ad_c2_w, ad_c2_b, nullptr, nullptr, WT, BIAS, 256, 256, 256, 256, 0, 16, 9);
    conv_mfma_k<9><<<gC2, b128, 0, stream>>>(DIFF, 16, nullptr, 0, WT, 256, BIAS, V, 256);
    wtx_k<<<(9 * 16 * 256 * 16 + 256 + 255) / 256, b256, 0, stream>>>(
        ad_c3_w, ad_c3_b, nullptr, nullptr, WT, BIAS, 256, 256, 256, 256, 0, 16, 9);
    conv_mfma_k<9><<<gC2, b128, 0, stream>>>(V, 16, nullptr, 0, WT, 256, BIAS, W, 256);

    // 15. reduce_conv2 (1x1 + BN) -> L48 (zero its borders first; overlays DIFF)
    borderzero_t_k<<<(580 * 4 + 255) / 256, b256, 0, stream>>>(L48, 4);
    wtx_k<<<(1 * 16 * 128 * 16 + 128 + 255) / 256, b256, 0, stream>>>(
        rc_w, rc_b, rc_g, rc_beta, WT, BIAS, 48, 128, 256, 256, 0, 16, 1);
    conv_mfma_k<1><<<gC1, b128, 0, stream>>>(F2t, 16, nullptr, 0, WT, 128, BIAS, L48, 64);

    // 16-18. last_conv (lc1: KBt padded 20->24 so nsteps%8==0; pad weights zero)
    wtx_k<<<(9 * 24 * 256 * 16 + 256 + 255) / 256, b256, 0, stream>>>(
        lc1_w, lc1_b, lc1_g, lc1_beta, WT, BIAS, 256, 256, 256, 256, 48, 24, 9);
    conv_mfma_k<9><<<gC2, b128, 0, stream>>>(W, 16, L48, 8, WT, 256, BIAS, U, 256);
    wtx_k<<<(9 * 16 * 256 * 16 + 256 + 255) / 256, b256, 0, stream>>>(
        lc2_w, lc2_b, lc2_g, lc2_beta, WT, BIAS, 256, 256, 256, 256, 0, 16, 9);
    conv_mfma_k<9><<<gC2, b128, 0, stream>>>(U, 16, nullptr, 0, WT, 256, BIAS, V, 256);
    wtx_k<<<(1 * 16 * 128 * 16 + 128 + 255) / 256, b256, 0, stream>>>(
        lc3_w, lc3_b, nullptr, nullptr, WT, BIAS, 19, 128, 256, 256, 0, 16, 1);
    conv_mfma_k<1><<<gC1, b128, 0, stream>>>(V, 16, nullptr, 0, WT, 128, BIAS, O19, 32);

    // 19. upsample
    upsample_k<<<(NOUT + 255) / 256, b256, 0, stream>>>(O19, out);
}

// Round 5
// 484.122 us; speedup vs baseline: 15.8226x; 1.2680x over previous
//
#include <hip/hip_runtime.h>
#include <math.h>

#define HWIMG 18432          // 96*192
#define W2 194               // padded width, pad=1
#define H2 98
#define NPX1 (H2 * W2)       // 19012 padded pixels, pad=1
#define W4 200               // padded width, pad=4
#define H4 104
#define NPX4 (H4 * W4)       // 20800 padded pixels, pad=4
#define NOUT (19 * 384 * 768)

typedef short bf16x8 __attribute__((ext_vector_type(8)));
typedef float f32x16 __attribute__((ext_vector_type(16)));

__device__ __forceinline__ ushort bf16r(float f) {
    union { float f; unsigned u; } a; a.f = f;
    unsigned u = a.u;
    return (ushort)((u + 0x7fffu + ((u >> 16) & 1u)) >> 16);
}
__device__ __forceinline__ float b2f(ushort u) {
    union { unsigned i; float f; } a; a.i = ((unsigned)u) << 16;
    return a.f;
}
__device__ __forceinline__ bf16x8 ld8(const ushort* p) {
    return *reinterpret_cast<const bf16x8*>(p);
}

// async global->LDS, 16B per lane. LDS dest: wave-uniform base + lane*16.
__device__ __forceinline__ void gld16(const ushort* g, ushort* l) {
    __builtin_amdgcn_global_load_lds(
        (const __attribute__((address_space(1))) unsigned int*)g,
        (__attribute__((address_space(3))) unsigned int*)l, 16, 0, 0);
}

#define MF(a, b, c) __builtin_amdgcn_mfma_f32_32x32x16_bf16(a, b, c, 0, 0, 0)

// ===========================================================================
// Tiled activation layout: act[cb][px][c16]  (cb = ch/16, px in padded pad=1
// image, c16 = ch%16). Weights: wt[kb][tap][ocp][16].
// ===========================================================================

// NCHW f32 -> tiled bf16 (full padded range, borders zeroed). optional src-src2.
__global__ __launch_bounds__(256) void xform_t_k(const float* __restrict__ src,
                                                 const float* __restrict__ src2,
                                                 ushort* __restrict__ dst)
{
    const int px = blockIdx.x * 32 + (threadIdx.x & 31);
    const int c8 = (blockIdx.y * 8 + (threadIdx.x >> 5)) * 8;
    if (px >= NPX1) return;
    const int yP = px / W2, xP = px % W2;
    const int y = yP - 1, x = xP - 1;
    ushort v[8];
    if (y >= 0 && y < 96 && x >= 0 && x < 192) {
        const int p = y * 192 + x;
#pragma unroll
        for (int j = 0; j < 8; ++j) {
            float f = src[(size_t)(c8 + j) * HWIMG + p];
            if (src2) f -= src2[(size_t)(c8 + j) * HWIMG + p];
            v[j] = bf16r(f);
        }
    } else {
#pragma unroll
        for (int j = 0; j < 8; ++j) v[j] = 0;
    }
    *reinterpret_cast<uint4*>(dst + ((size_t)(c8 >> 4) * NPX1 + px) * 16 + (c8 & 15))
        = *reinterpret_cast<uint4*>(v);
}

// NCHW f32 -> padded NHWC bf16 (pad=4), for the propagation input only.
__global__ __launch_bounds__(256) void xform_nhwc_k(const float* __restrict__ src,
                                                    ushort* __restrict__ dst)
{
    const int px = blockIdx.x * 8 + (threadIdx.x >> 5);
    const int c8 = (threadIdx.x & 31) * 8;
    if (px >= NPX4) return;
    const int yP = px / W4, xP = px % W4;
    const int y = yP - 4, x = xP - 4;
    ushort v[8];
    if (y >= 0 && y < 96 && x >= 0 && x < 192) {
        const int p = y * 192 + x;
#pragma unroll
        for (int j = 0; j < 8; ++j) v[j] = bf16r(src[(size_t)(c8 + j) * HWIMG + p]);
    } else {
#pragma unroll
        for (int j = 0; j < 8; ++j) v[j] = 0;
    }
    *reinterpret_cast<uint4*>(dst + (size_t)px * 256 + c8) = *reinterpret_cast<uint4*>(v);
}

// Zero pad=1 border pixels of three 16-cb tiled buffers.
__global__ __launch_bounds__(256) void borderzero3_k(ushort* __restrict__ b0,
                                                     ushort* __restrict__ b1,
                                                     ushort* __restrict__ b2)
{
    ushort* buf = (blockIdx.y == 0) ? b0 : ((blockIdx.y == 1) ? b1 : b2);
    const int idx = blockIdx.x * 256 + threadIdx.x;
    if (idx >= 580 * 16) return;
    const int pi = idx % 580;
    const int cb = idx / 580;
    int pp;
    if (pi < 194) pp = pi;
    else if (pi < 388) pp = 97 * 194 + (pi - 194);
    else if (pi < 484) pp = (pi - 388 + 1) * 194;
    else pp = (pi - 484 + 1) * 194 + 193;
    uint4 z = {0, 0, 0, 0};
    ushort* p = buf + ((size_t)cb * NPX1 + pp) * 16;
    *reinterpret_cast<uint4*>(p) = z;
    *reinterpret_cast<uint4*>(p + 8) = z;
}

// ---------------------------------------------------------------------------
// Batched weight transform: OIHW f32 -> wt[kb][tap][ocp][16] bf16 + bias f32.
// ---------------------------------------------------------------------------
struct WtxJob {
    const float* w; const float* b; const float* g; const float* beta;
    int CoutR, Coutp, CinR0, kb0e, CinR1, KBt, ntaps, wtoff, biasoff;
};

__global__ __launch_bounds__(256) void wtx_multi_k(WtxJob J0, WtxJob J1, WtxJob J2,
                                                   WtxJob J3, WtxJob J4, WtxJob J5,
                                                   ushort* __restrict__ wt,
                                                   float* __restrict__ biasout)
{
    WtxJob J = J0;
    switch (blockIdx.y) {
        case 1: J = J1; break; case 2: J = J2; break; case 3: J = J3; break;
        case 4: J = J4; break; case 5: J = J5; break; default: break;
    }
    const int idx = blockIdx.x * 256 + threadIdx.x;
    const int total = J.ntaps * J.KBt * J.Coutp * 16;
    const int CinT = J.CinR0 + J.CinR1;
    if (idx < total) {
        const int c16 = idx & 15;
        const int oc = (idx >> 4) % J.Coutp;
        const int r2 = idx / (16 * J.Coutp);
        const int tap = r2 % J.ntaps;
        const int kbt = r2 / J.ntaps;
        const int k = kbt * 16 + c16;
        float val = 0.f;
        if (oc < J.CoutR) {
            int cit = -1;
            if (k < J.kb0e) { if (k < J.CinR0) cit = k; }
            else { const int k1 = k - J.kb0e; if (k1 < J.CinR1) cit = J.CinR0 + k1; }
            if (cit >= 0) {
                val = J.w[((size_t)oc * CinT + cit) * J.ntaps + tap];
                if (J.g) val *= J.g[oc];
            }
        }
        wt[J.wtoff + idx] = bf16r(val);
    } else if (idx < total + J.Coutp) {
        const int oc = idx - total;
        float v = 0.f;
        if (oc < J.CoutR) {
            v = J.b ? J.b[oc] : 0.f;
            if (J.g) v = v * J.g[oc] + J.beta[oc];
        }
        biasout[J.biasoff + oc] = v;
    }
}

// ---------------------------------------------------------------------------
// LDS-staged implicit-GEMM conv (m97 structure). Block 256 thr = 4 waves,
// tile 128px (2 rows x 64) x 128 oc; wave 64px x 64oc. Per kb: stage A-halo +
// B (9 taps) via global_load_lds, barrier, 9x{4 ds_read_b128, 4 MFMA}, barrier.
// grid.x = 144 * Coutp/128 (XCD-swizzled), grid.y = job.
// ---------------------------------------------------------------------------
struct ConvJob {
    const ushort* in0; const ushort* in1;
    int KB0, KB1;
    const ushort* wt;
    const float* bias;
    ushort* out;
    int CoutWr;            // writable channels (multiple of 32)
};

template<int NTAPS>
__global__ __launch_bounds__(256) void conv_lds_k(ConvJob j0, ConvJob j1, ConvJob j2,
                                                  int Coutp)
{
    constexpr int AROWS = (NTAPS == 9) ? 4 : 2;
    constexpr int AW = (NTAPS == 9) ? 66 : 64;
    constexpr int ASLOTS = AROWS * AW * 2;            // 16B slots: 528 or 256
    __shared__ __align__(16) ushort Abuf[AROWS * AW * 16];
    __shared__ __align__(16) ushort Bbuf[NTAPS * 128 * 16];

    ConvJob J = j0;
    if (blockIdx.y == 1) J = j1;
    else if (blockIdx.y == 2) J = j2;

    const int nblk = gridDim.x;
    const int cpx = nblk >> 3;                        // nblk % 8 == 0
    const int sw = ((int)blockIdx.x & 7) * cpx + ((int)blockIdx.x >> 3);
    const int pt = sw % 144;
    const int ocb0 = (sw / 144) * 128;
    const int y0 = (pt / 3) * 2 + 1;
    const int x0 = (pt % 3) * 64 + 1;

    const int tid = threadIdx.x;
    const int lane = tid & 63;
    const int wave = tid >> 6;
    const int wm = wave & 1, wn = wave >> 1;
    const int l31 = lane & 31;
    const int klo8 = (lane >> 5) * 8;

    const int KBtot = J.KB0 + J.KB1;

    f32x16 c00 = {}, c01 = {}, c10 = {}, c11 = {};

    for (int kb = 0; kb < KBtot; ++kb) {
        const ushort* plane = (kb < J.KB0)
            ? (J.in0 + (size_t)kb * (NPX1 * 16))
            : (J.in1 + (size_t)(kb - J.KB0) * (NPX1 * 16));

        // ---- stage A-halo ----
#pragma unroll
        for (int i = 0; i < (ASLOTS + 255) / 256; ++i) {
            const int f16 = i * 256 + tid;
            if ((ASLOTS % 256 == 0) || (f16 < ASLOTS)) {
                const int e = f16 >> 1;
                const int r = e / AW;
                const int xx = e - r * AW;
                const int px = (NTAPS == 9)
                    ? (y0 - 1 + r) * W2 + (x0 - 1 + xx)
                    : (y0 + r) * W2 + (x0 + xx);
                const ushort* src = plane + (size_t)px * 16 + (f16 & 1) * 8;
                const int wub = (f16 & ~63) * 16;     // wave-uniform LDS byte off
                gld16(src, (ushort*)((char*)Abuf + __builtin_amdgcn_readfirstlane(wub)));
            }
        }
        // ---- stage B ----
        {
            const ushort* wsrc = J.wt + ((size_t)kb * NTAPS * Coutp + ocb0) * 16
                               + (size_t)tid * 8;
#pragma unroll
            for (int t = 0; t < NTAPS; ++t) {
                const ushort* src = wsrc + (size_t)t * Coutp * 16;
                const int wub = t * 4096 + (tid & ~63) * 16;
                gld16(src, (ushort*)((char*)Bbuf + __builtin_amdgcn_readfirstlane(wub)));
            }
        }
        __syncthreads();   // drains vmcnt (compiler emits vmcnt(0) before s_barrier)

        // ---- compute ----
#pragma unroll
        for (int t = 0; t < NTAPS; ++t) {
            int entA;
            if (NTAPS == 9) entA = (wm + t / 3) * AW + (t % 3) + l31;
            else            entA = wm * 64 + l31;
            bf16x8 a0 = ld8(&Abuf[entA * 16 + klo8]);
            bf16x8 a1 = ld8(&Abuf[(entA + 32) * 16 + klo8]);
            const int entB = t * 128 + wn * 64 + l31;
            bf16x8 b0 = ld8(&Bbuf[entB * 16 + klo8]);
            bf16x8 b1 = ld8(&Bbuf[(entB + 32) * 16 + klo8]);
            c00 = MF(a0, b0, c00);
            c01 = MF(a0, b1, c01);
            c10 = MF(a1, b0, c10);
            c11 = MF(a1, b1, c11);
        }
        __syncthreads();   // protect LDS before next-kb staging
    }

    // ---- epilogue (validated C/D mapping) ----
    const int pxbase = (y0 + wm) * W2 + x0;
    const int rlo = (lane >> 5) * 4;
#pragma unroll
    for (int j = 0; j < 2; ++j) {
        if (ocb0 + wn * 64 + j * 32 + 32 > J.CoutWr) continue;  // wave-uniform
        const int oc = ocb0 + wn * 64 + j * 32 + l31;
        const float bs = J.bias[oc];
        const size_t obase = (size_t)(oc >> 4) * ((size_t)NPX1 * 16) + (oc & 15);
        const f32x16 v0 = j ? c01 : c00;
        const f32x16 v1 = j ? c11 : c10;
#pragma unroll
        for (int r = 0; r < 16; ++r) {
            const int rw = (r & 3) + 8 * (r >> 2) + rlo;
            J.out[obase + (size_t)(pxbase + rw) * 16] = bf16r(v0[r] + bs);
            J.out[obase + (size_t)(pxbase + 32 + rw) * 16] = bf16r(v1[r] + bs);
        }
    }
}

// ---------------------------------------------------------------------------
// Softmax over 81 channels (tiled layout), in place, interior pixels.
// ---------------------------------------------------------------------------
__global__ __launch_bounds__(256) void softmax81_k(ushort* __restrict__ t)
{
    const int p = blockIdx.x * 256 + threadIdx.x;
    if (p >= HWIMG) return;
    const int y = p / 192, x = p % 192;
    const size_t pp = (size_t)(y + 1) * W2 + (x + 1);
    float v[81];
    float m = -1e30f;
#pragma unroll
    for (int k = 0; k < 81; ++k) {
        v[k] = b2f(t[((size_t)(k >> 4) * NPX1 + pp) * 16 + (k & 15)]);
        m = fmaxf(m, v[k]);
    }
    float s = 0.f;
#pragma unroll
    for (int k = 0; k < 81; ++k) { v[k] = __expf(v[k] - m); s += v[k]; }
    const float inv = 1.f / s;
#pragma unroll
    for (int k = 0; k < 81; ++k)
        t[((size_t)(k >> 4) * NPX1 + pp) * 16 + (k & 15)] = bf16r(v[k] * inv);
}

// ---------------------------------------------------------------------------
// Propagation: out[px][c] = sum_k deep[y+dy][x+dx][c] * ker[px][k]
// deep: pad4 NHWC bf16; ker: tiled (6 cb used); out: tiled, FULL write.
// ---------------------------------------------------------------------------
__global__ __launch_bounds__(256) void prop_k(const ushort* __restrict__ deep,
                                              const ushort* __restrict__ ker,
                                              ushort* __restrict__ out)
{
    __shared__ float kl[8][81];
    const int pxb = blockIdx.x * 8;
    const int t = threadIdx.x;
    for (int i = t; i < 8 * 81; i += 256) {
        const int pp = pxb + i / 81, k = i % 81;
        float kv = 0.f;
        if (pp < NPX1) {
            const int yP = pp / W2, xP = pp % W2;
            if (yP >= 1 && yP <= 96 && xP >= 1 && xP <= 192)
                kv = b2f(ker[((size_t)(k >> 4) * NPX1 + pp) * 16 + (k & 15)]);
        }
        kl[i / 81][k] = kv;
    }
    __syncthreads();
    const int pi = t >> 5;
    const int c8 = (t & 31) * 8;
    const int pp = pxb + pi;
    if (pp >= NPX1) return;
    const int yP = pp / W2, xP = pp % W2;
    ushort* op = out + ((size_t)(c8 >> 4) * NPX1 + pp) * 16 + (c8 & 15);
    if (yP < 1 || yP > 96 || xP < 1 || xP > 192) {
        uint4 z = {0, 0, 0, 0};
        *reinterpret_cast<uint4*>(op) = z;
        return;
    }
    const int y = yP - 1, x = xP - 1;
    float acc[8];
#pragma unroll
    for (int j = 0; j < 8; ++j) acc[j] = 0.f;
    const ushort* dbase = deep + ((size_t)(y + 4) * W4 + (x + 4)) * 256 + c8;
#pragma unroll
    for (int k = 0; k < 81; ++k) {
        const int dy = k / 9 - 4, dx = k % 9 - 4;
        const float kv = kl[pi][k];
        bf16x8 d = ld8(dbase + (ptrdiff_t)(dy * W4 + dx) * 256);
#pragma unroll
        for (int j = 0; j < 8; ++j) acc[j] += b2f((ushort)d[j]) * kv;
    }
    ushort v[8];
#pragma unroll
    for (int j = 0; j < 8; ++j) v[j] = bf16r(acc[j]);
    *reinterpret_cast<uint4*>(op) = *reinterpret_cast<uint4*>(v);
}

// ---------------------------------------------------------------------------
// Per-row channel sums (tiled input): partial[y][c]
// ---------------------------------------------------------------------------
__global__ __launch_bounds__(256) void rowsum_k(const ushort* __restrict__ t,
                                                float* __restrict__ partial)
{
    const int y = blockIdx.x, c = threadIdx.x;
    const size_t base = ((size_t)(c >> 4) * NPX1 + (size_t)(y + 1) * W2 + 1) * 16 + (c & 15);
    float s = 0.f;
    for (int x = 0; x < 192; ++x) s += b2f(t[base + (size_t)x * 16]);
    partial[y * 256 + c] = s;
}

__global__ __launch_bounds__(256) void dev_k(const float* __restrict__ partial,
                                             const float* __restrict__ fcw,
                                             const float* __restrict__ fcb,
                                             float* __restrict__ o)
{
    __shared__ float buf[256];
    const int c = threadIdx.x;
    float s = 0.f;
    for (int y = 0; y < 96; ++y) s += partial[y * 256 + c];
    buf[c] = s * fcw[c];
    __syncthreads();
    for (int st = 128; st > 0; st >>= 1) {
        if (c < st) buf[c] += buf[c + st];
        __syncthreads();
    }
    if (c == 0) o[0] = buf[0] * (1.f / (float)HWIMG) + fcb[0];
}

// ---------------------------------------------------------------------------
// 4x bilinear upsample from tiled bf16 (19 ch used) -> f32 NCHW
// ---------------------------------------------------------------------------
__global__ __launch_bounds__(256) void upsample_k(const ushort* __restrict__ in,
                                                  float* __restrict__ outp)
{
    const int idx = blockIdx.x * 256 + threadIdx.x;
    if (idx >= NOUT) return;
    const int ox = idx % 768;
    const int t = idx / 768;
    const int oy = t % 384;
    const int c = t / 384;

    const float fx = (ox + 0.5f) * 0.25f - 0.5f;
    const float fy = (oy + 0.5f) * 0.25f - 0.5f;
    const int x0 = (int)floorf(fx);
    const int y0 = (int)floorf(fy);
    const float wx = fx - (float)x0;
    const float wy = fy - (float)y0;
    const int x0c = min(max(x0, 0), 191), x1c = min(max(x0 + 1, 0), 191);
    const int y0c = min(max(y0, 0), 95), y1c = min(max(y0 + 1, 0), 95);

    const size_t cb = (size_t)(c >> 4) * NPX1;
    const int c16 = c & 15;
    const float v00 = b2f(in[(cb + (size_t)(y0c + 1) * W2 + (x0c + 1)) * 16 + c16]);
    const float v01 = b2f(in[(cb + (size_t)(y0c + 1) * W2 + (x1c + 1)) * 16 + c16]);
    const float v10 = b2f(in[(cb + (size_t)(y1c + 1) * W2 + (x0c + 1)) * 16 + c16]);
    const float v11 = b2f(in[(cb + (size_t)(y1c + 1) * W2 + (x1c + 1)) * 16 + c16]);
    outp[idx] = (1.f - wy) * ((1.f - wx) * v00 + wx * v01)
              + wy * ((1.f - wx) * v10 + wx * v11);
}

// ---------------------------------------------------------------------------
extern "C" void kernel_launch(void* const* d_in, const int* in_sizes, int n_in,
                              void* d_out, int out_size, void* d_ws, size_t ws_size,
                              hipStream_t stream)
{
    const float* f1_deep = (const float*)d_in[0];
    const float* f1_low  = (const float*)d_in[1];
    const float* f2_low  = (const float*)d_in[2];
    const float* wp_c1_w = (const float*)d_in[3];
    const float* wp_c1_b = (const float*)d_in[4];
    const float* wp_c2_w = (const float*)d_in[5];
    const float* wp_c2_b = (const float*)d_in[6];
    const float* wp_fc_w = (const float*)d_in[7];
    const float* wp_fc_b = (const float*)d_in[8];
    const float* sch_c1_w = (const float*)d_in[9];
    const float* sch_c2_w = (const float*)d_in[11];
    const float* sch_c2_b = (const float*)d_in[12];
    const float* sch_fc_w = (const float*)d_in[13];
    const float* sch_fc_b = (const float*)d_in[14];
    const float* ad_c1_w = (const float*)d_in[15];
    const float* ad_c1_b = (const float*)d_in[16];
    const float* ad_c2_w = (const float*)d_in[17];
    const float* ad_c2_b = (const float*)d_in[18];
    const float* ad_c3_w = (const float*)d_in[19];
    const float* ad_c3_b = (const float*)d_in[20];
    const float* rc_w    = (const float*)d_in[21];
    const float* rc_b    = (const float*)d_in[22];
    const float* rc_g    = (const float*)d_in[23];
    const float* rc_beta = (const float*)d_in[24];
    const float* lc1_w   = (const float*)d_in[25];
    const float* lc1_b   = (const float*)d_in[26];
    const float* lc1_g   = (const float*)d_in[27];
    const float* lc1_beta= (const float*)d_in[28];
    const float* lc2_w   = (const float*)d_in[29];
    const float* lc2_b   = (const float*)d_in[30];
    const float* lc2_g   = (const float*)d_in[31];
    const float* lc2_beta= (const float*)d_in[32];
    const float* lc3_w   = (const float*)d_in[33];
    const float* lc3_b   = (const float*)d_in[34];

    float* out = (float*)d_out;
    ushort* ws0 = (ushort*)d_ws;

    const size_t CBBe  = (size_t)NPX1 * 256;   // elems of one 16-cb tiled buffer
    const size_t BUF0e = (size_t)NPX4 * 256;   // pad4 NHWC deep buffer elems

    ushort* Bb = ws0 + BUF0e;            // slot B
    ushort* Cb = Bb + CBBe;              // slot C
    ushort* Db = Cb + CBBe;              // slot D
    ushort* Eb = Db + CBBe;              // slot E
    ushort* Fb = Eb + CBBe;              // slot F
    ushort* WT = Fb + CBBe;              // weights: 3,719,168 elems
    float* BIAS = (float*)(WT + 3719168);
    float* PART = BIAS + 12 * 256;
    ushort* L48 = Eb + 6 * (size_t)NPX1 * 16;   // cb6-9 of slot E

    const dim3 b256(256);

    // 1. input transforms (full writes incl. zero borders)
    xform_t_k<<<dim3(595, 4), b256, 0, stream>>>(f1_low, nullptr, Bb);
    xform_t_k<<<dim3(595, 4), b256, 0, stream>>>(f2_low, nullptr, Cb);
    xform_t_k<<<dim3(595, 4), b256, 0, stream>>>(f1_low, f2_low, Db);
    // 2. zero borders of conv-output slots that get halo-read (stay zero after)
    borderzero3_k<<<dim3(37, 3), b256, 0, stream>>>(ws0, Eb, Fb);

    // 3. weight transforms, phase 1
    {
        WtxJob w0 = {wp_c1_w, wp_c1_b, nullptr, nullptr, 256, 256, 256, 256, 0, 16, 9, 0, 0};
        WtxJob w1 = {sch_c1_w, nullptr, nullptr, nullptr, 256, 256, 256, 256, 0, 16, 9, 589824, 256};
        WtxJob w2 = {wp_c2_w, wp_c2_b, nullptr, nullptr, 256, 256, 256, 256, 256, 32, 9, 1179648, 512};
        WtxJob w3 = {sch_c2_w, sch_c2_b, nullptr, nullptr, 256, 256, 256, 256, 0, 16, 9, 2359296, 768};
        WtxJob w4 = {wp_fc_w, wp_fc_b, nullptr, nullptr, 81, 128, 256, 256, 0, 16, 1, 2949120, 1024};
        WtxJob w5 = {rc_w, rc_b, rc_g, rc_beta, 48, 128, 256, 256, 0, 16, 1, 2981888, 1280};
        wtx_multi_k<<<dim3(4610, 6), b256, 0, stream>>>(w0, w1, w2, w3, w4, w5, WT, BIAS);
    }

    // 4. batch A: wp_c1(F1)->E, wp_c1(F2)->F, sch_c1(DIFF)->SCH1(ws0)
    {
        ConvJob a0 = {Bb, Bb, 16, 0, WT, BIAS, Eb, 256};
        ConvJob a1 = {Cb, Cb, 16, 0, WT, BIAS, Fb, 256};
        ConvJob a2 = {Db, Db, 16, 0, WT + 589824, BIAS + 256, ws0, 256};
        conv_lds_k<9><<<dim3(288, 3), b256, 0, stream>>>(a0, a1, a2, 256);
    }
    // 5. batch B: wp_c2(E,F)->D ; sch_c2(SCH1)->B
    {
        ConvJob a0 = {Eb, Fb, 16, 16, WT + 1179648, BIAS + 512, Db, 256};
        ConvJob a1 = {ws0, ws0, 16, 0, WT + 2359296, BIAS + 768, Bb, 256};
        conv_lds_k<9><<<dim3(288, 2), b256, 0, stream>>>(a0, a1, a0, 256);
    }
    // 6. deviation branch
    rowsum_k<<<96, b256, 0, stream>>>(Bb, PART);
    dev_k<<<1, b256, 0, stream>>>(PART, sch_fc_w, sch_fc_b, out + NOUT);

    // 7. batch 1x1: fc(D)->K81(E cb0-5) ; rc(F2)->L48(E cb6-9)
    {
        ConvJob a0 = {Db, Db, 16, 0, WT + 2949120, BIAS + 1024, Eb, 96};
        ConvJob a1 = {Cb, Cb, 16, 0, WT + 2981888, BIAS + 1280, L48, 64};
        conv_lds_k<1><<<dim3(144, 2), b256, 0, stream>>>(a0, a1, a0, 128);
    }

    // 8. weight transforms, phase 2
    {
        WtxJob w0 = {ad_c1_w, ad_c1_b, nullptr, nullptr, 256, 256, 256, 256, 256, 32, 9, 0, 1536};
        WtxJob w1 = {ad_c2_w, ad_c2_b, nullptr, nullptr, 256, 256, 256, 256, 0, 16, 9, 1179648, 1792};
        WtxJob w2 = {ad_c3_w, ad_c3_b, nullptr, nullptr, 256, 256, 256, 256, 0, 16, 9, 1769472, 2048};
        WtxJob w3 = {lc1_w, lc1_b, lc1_g, lc1_beta, 256, 256, 256, 256, 48, 20, 9, 2359296, 2304};
        WtxJob w4 = {lc2_w, lc2_b, lc2_g, lc2_beta, 256, 256, 256, 256, 0, 16, 9, 3096576, 2560};
        WtxJob w5 = {lc3_w, lc3_b, nullptr, nullptr, 19, 128, 256, 256, 0, 16, 1, 3686400, 2816};
        wtx_multi_k<<<dim3(4610, 6), b256, 0, stream>>>(w0, w1, w2, w3, w4, w5, WT, BIAS);
    }

    // 9. softmax + propagation
    softmax81_k<<<72, b256, 0, stream>>>(Eb);
    xform_nhwc_k<<<2600, b256, 0, stream>>>(f1_deep, ws0);
    prop_k<<<2377, b256, 0, stream>>>(ws0, Eb, Fb);

    // 10. AdaptNet
    {
        ConvJob a = {Cb, Fb, 16, 16, WT, BIAS + 1536, Bb, 256};
        conv_lds_k<9><<<dim3(288, 1), b256, 0, stream>>>(a, a, a, 256);
    }
    {
        ConvJob a = {Bb, Bb, 16, 0, WT + 1179648, BIAS + 1792, Db, 256};
        conv_lds_k<9><<<dim3(288, 1), b256, 0, stream>>>(a, a, a, 256);
    }
    {
        ConvJob a = {Db, Db, 16, 0, WT + 1769472, BIAS + 2048, Fb, 256};
        conv_lds_k<9><<<dim3(288, 1), b256, 0, stream>>>(a, a, a, 256);
    }
    // 11. last_conv
    {
        ConvJob a = {Fb, L48, 16, 4, WT + 2359296, BIAS + 2304, Bb, 256};
        conv_lds_k<9><<<dim3(288, 1), b256, 0, stream>>>(a, a, a, 256);
    }
    {
        ConvJob a = {Bb, Bb, 16, 0, WT + 3096576, BIAS + 2560, Db, 256};
        conv_lds_k<9><<<dim3(288, 1), b256, 0, stream>>>(a, a, a, 256);
    }
    {
        ConvJob a = {Db, Db, 16, 0, WT + 3686400, BIAS + 2816, Cb, 32};
        conv_lds_k<1><<<dim3(144, 1), b256, 0, stream>>>(a, a, a, 128);
    }

    // 12. upsample
    upsample_k<<<(NOUT + 255) / 256, b256, 0, stream>>>(Cb, out);
}